// Round 8
// baseline (2094.264 us; speedup 1.0000x reference)
//
#include <hip/hip_runtime.h>
#include <hip/hip_cooperative_groups.h>
#include <hip/hip_bf16.h>
#include <cstddef>

namespace cg = cooperative_groups;

// Problem constants
#define NB 64      // batch
#define LL 128     // L1 == L2
#define EE 300     // embed dim
#define DD 256     // hidden dim
#define NLAYERS 10
#define MROWS (NB * LL)  // 8192

static constexpr float BN_SC = 0.9995003746877562f;  // 1/sqrt(1+1e-3)

typedef unsigned short u16;
typedef __attribute__((ext_vector_type(4))) unsigned short us4;
typedef __attribute__((ext_vector_type(8))) unsigned short us8;
typedef __attribute__((ext_vector_type(8))) short bfrag;   // 8 bf16 (4 VGPR)
typedef __attribute__((ext_vector_type(4))) float f4;      // MFMA C/D

#define MFMA_B16(a, b, c) __builtin_amdgcn_mfma_f32_16x16x32_bf16(a, b, c, 0, 0, 0)

__device__ __forceinline__ u16 f2bf(float x) {
  union { float f; unsigned u; } v; v.f = x;
  unsigned r = v.u + 0x7FFFu + ((v.u >> 16) & 1u);  // RNE
  return (u16)(r >> 16);
}
__device__ __forceinline__ float bf2f(u16 s) {
  union { unsigned u; float f; } v; v.u = (unsigned)s << 16;
  return v.f;
}
__device__ __forceinline__ float4 ld4(const float* p) { return *(const float4*)p; }

// direct MFMA fragment load from row-major [row][k] bf16 global (L2-hot)
__device__ __forceinline__ bfrag gfrag(const u16* __restrict__ p, int ld, int row, int k) {
  return *(const bfrag*)(p + (size_t)row * ld + k);
}

// swizzled byte offset into a [128][128] bf16 LDS matrix (conflict-free b128 reads)
__device__ __forceinline__ int eswz(int row, int colbyte) {
  return (row * 256 + colbyte) ^ ((row & 7) << 4);
}
__device__ __forceinline__ bfrag ldsE(const u16* E, int row, int colbyte) {
  return *(const bfrag*)((const char*)E + eswz(row, colbyte));
}

struct MArgs {
  const float *embed, *W1f, *W1r, *b1, *bn1g, *bn1b;
  const float *W2, *b2, *bn2g, *bn2b, *Wg, *bg;
  const float *Wf1, *bf1, *Wf2, *bf2, *Wout, *bout;
  const int *ids1, *ids2;
  u16 *H1, *H2, *HT1, *HT2, *X1, *X2, *BETA, *ALPHA;
  float *SQP1, *SQP2;
  u16 *Wt1f, *Wt1r, *Wt2, *Wtg, *Wf1t, *Wf2t;
  u16 *VPh, *VPl, *T1h, *T1l;
  float *T2f, *PART1, *PART2;
  float *outp;
};

#define SMEM_BYTES 35840

// ---------------- weight transpose tile: dst[n][k]=bf16(src[k][n]) -------
__device__ void txw_tile(const float* __restrict__ src, u16* __restrict__ dst,
                         int K, int N, int Kpad, int k0, int n0, int t, char* smem) {
  float (*tileS)[65] = (float(*)[65])smem;
  __syncthreads();  // protect previous LDS use
  {
    const int kr = t >> 2, nc = (t & 3) * 16;
    const int k = k0 + kr;
#pragma unroll
    for (int j = 0; j < 16; j += 4) {
      float4 v = (k < K) ? ld4(src + (size_t)k * N + n0 + nc + j)
                         : make_float4(0.f, 0.f, 0.f, 0.f);
      tileS[kr][nc + j + 0] = v.x; tileS[kr][nc + j + 1] = v.y;
      tileS[kr][nc + j + 2] = v.z; tileS[kr][nc + j + 3] = v.w;
    }
  }
  __syncthreads();
  {
    const int nr = t >> 2, kc = (t & 3) * 16;
    us8 o0, o1;
#pragma unroll
    for (int j = 0; j < 8; ++j) {
      o0[j] = f2bf(tileS[kc + j][nr]);
      o1[j] = f2bf(tileS[kc + 8 + j][nr]);
    }
    u16* d = dst + (size_t)(n0 + nr) * Kpad + k0 + kc;
    *(us8*)d = o0;
    *(us8*)(d + 8) = o1;
  }
}

// ---------------- embed gather (4 rows per task) -------------------------
__device__ void gather4(const MArgs& A, int g, int t) {
  const int side = g & 1;
  const int gg = g >> 1;
  const int* ids = side ? A.ids2 : A.ids1;
  u16* E = side ? A.X2 : A.X1;
  const int row = gg * 4 + (t >> 6);
  const int lane = t & 63;
  const float* src = A.embed + (size_t)ids[row] * EE;
  u16* dst = E + (size_t)row * 320;
#pragma unroll
  for (int j = 0; j < 5; ++j) {
    const int c = lane + 64 * j;
    dst[c] = f2bf(c < EE ? src[c] : 0.f);
  }
}

__device__ void prologue(const MArgs& A, int blk, int nblk, int t, char* smem) {
  for (int it = blk; it < 20; it += nblk)
    txw_tile(A.W1f, A.Wt1f, 300, 256, 320, (it % 5) * 64, (it / 5) * 64, t, smem);
  for (int it = blk; it < 144; it += nblk) {
    const int l = it / 16, r = it % 16;
    txw_tile(A.W1r + (size_t)l * 65536, A.Wt1r + (size_t)l * 65536, 256, 256, 256,
             (r % 4) * 64, (r / 4) * 64, t, smem);
  }
  for (int it = blk; it < 320; it += nblk) {
    const int l = it / 32, r = it % 32;
    txw_tile(A.W2 + (size_t)l * 131072, A.Wt2 + (size_t)l * 131072, 512, 256, 512,
             (r % 8) * 64, (r / 8) * 64, t, smem);
  }
  for (int it = blk; it < 160; it += nblk) {
    const int l = it / 16, r = it % 16;
    txw_tile(A.Wg + (size_t)l * 65536, A.Wtg + (size_t)l * 65536, 256, 256, 256,
             (r % 4) * 64, (r / 4) * 64, t, smem);
  }
  for (int it = blk; it < 256; it += nblk)
    txw_tile(A.Wf1, A.Wf1t, 1024, 1024, 1024, (it % 16) * 64, (it / 16) * 64, t, smem);
  for (int it = blk; it < 256; it += nblk)
    txw_tile(A.Wf2, A.Wf2t, 1024, 1024, 1024, (it % 16) * 64, (it / 16) * 64, t, smem);
  for (int g = blk; g < 4096; g += nblk) gather4(A, g, t);
}

// ---------------- LBR-1 no-LDS (+H^T, +sq-norm partials) -----------------
template <int NT>
__device__ __forceinline__ void lbr_core(const u16* __restrict__ Ap, int lda, int am0,
                                         const u16* __restrict__ Bp, int ldb, int bn0,
                                         int fr, int fq, f4 acc[4][2]) {
#pragma unroll
  for (int ks = 0; ks < NT; ++ks) {
    bfrag a[4], b[2];
#pragma unroll
    for (int mi = 0; mi < 4; ++mi)
      a[mi] = gfrag(Ap, lda, am0 + mi * 16 + fr, ks * 32 + fq * 8);
#pragma unroll
    for (int nj = 0; nj < 2; ++nj)
      b[nj] = gfrag(Bp, ldb, bn0 + nj * 16 + fr, ks * 32 + fq * 8);
#pragma unroll
    for (int mi = 0; mi < 4; ++mi)
#pragma unroll
      for (int nj = 0; nj < 2; ++nj) acc[mi][nj] = MFMA_B16(a[mi], b[nj], acc[mi][nj]);
  }
}

__device__ void phase_lbr(const MArgs& A, int layer, int blk, int t) {
  const int side = blk >> 8;
  const int rem = blk & 255;
  const int m0 = (rem >> 2) * 128;
  const int n0 = (rem & 3) * 64;
  const u16* X = side ? A.X2 : A.X1;
  u16* H = side ? A.H2 : A.H1;
  u16* HT = side ? A.HT2 : A.HT1;
  float* SQP = side ? A.SQP2 : A.SQP1;
  const u16* W1t = (layer == 0) ? A.Wt1f : (A.Wt1r + (size_t)(layer - 1) * 65536);
  const float* b1v = A.b1 + layer * DD;
  const float* g1v = A.bn1g + layer * DD;
  const float* be1v = A.bn1b + layer * DD;
  const int lane = t & 63, w = t >> 6;
  const int wm = w >> 1, wn = w & 1;
  const int fr = lane & 15, fq = lane >> 4;
  f4 acc[4][2] = {};
  if (layer == 0) lbr_core<10>(X, 320, m0 + wm * 64, W1t, 320, n0 + wn * 32, fr, fq, acc);
  else            lbr_core<8>(X, DD, m0 + wm * 64, W1t, DD, n0 + wn * 32, fr, fq, acc);
  const int bb = m0 >> 7;
  float rsq[4][4] = {};
#pragma unroll
  for (int nj = 0; nj < 2; ++nj) {
    const int n = n0 + wn * 32 + nj * 16 + fr;
    const float sc = g1v[n] * BN_SC, bi = b1v[n], be = be1v[n];
#pragma unroll
    for (int mi = 0; mi < 4; ++mi) {
      const int m = m0 + wm * 64 + mi * 16 + fq * 4;
      us4 pk;
#pragma unroll
      for (int r = 0; r < 4; ++r) {
        const float x = sc * (acc[mi][nj][r] + bi) + be;
        const u16 hb = f2bf(fmaxf(x, 0.f));
        H[(size_t)(m + r) * DD + n] = hb;
        pk[r] = hb;
        const float h = bf2f(hb);  // norms must match stored bf16 H
        rsq[mi][r] += h * h;
      }
      *(us4*)&HT[((size_t)bb * DD + n) * LL + (m & 127)] = pk;
    }
  }
#pragma unroll
  for (int mi = 0; mi < 4; ++mi)
#pragma unroll
    for (int r = 0; r < 4; ++r) {
      float v = rsq[mi][r];
      v += __shfl_xor(v, 1, 64); v += __shfl_xor(v, 2, 64);
      v += __shfl_xor(v, 4, 64); v += __shfl_xor(v, 8, 64);
      rsq[mi][r] = v;
    }
  if (fr == 0) {
    const int p = (rem & 3) * 2 + wn;  // 8 partials per row
#pragma unroll
    for (int mi = 0; mi < 4; ++mi)
#pragma unroll
      for (int r = 0; r < 4; ++r)
        SQP[(size_t)p * MROWS + m0 + wm * 64 + mi * 16 + fq * 4 + r] = rsq[mi][r];
  }
}

// ---------------- fused att+attn per (batch, nh, side) -------------------
__device__ void phase_att(const MArgs& A, int blk, int t, char* smem) {
  u16* Elds = (u16*)smem;                    // 32KB swizzled
  float* sq1 = (float*)(smem + 32768);       // [128]
  float* sq2 = sq1 + 128;                    // [128]
  float* rowp = sq2 + 128;                   // [2][128]
  float* colp = rowp + 256;                  // [2][128]
  const int side = blk >> 7;
  const int rem = blk & 127;
  const int b = rem >> 1, nh = rem & 1;
  const int lane = t & 63, w = t >> 6;
  const int wm = w >> 1, wn = w & 1;
  const int fr = lane & 15, fq = lane >> 4;
  const int r0 = b * LL;
  __syncthreads();  // protect smem across phase_att task iterations
  if (t < 128) {
    float s = 0.f;
#pragma unroll
    for (int p = 0; p < 8; ++p) s += A.SQP1[(size_t)p * MROWS + r0 + t];
    sq1[t] = s;
  } else {
    const int u = t - 128;
    float s = 0.f;
#pragma unroll
    for (int p = 0; p < 8; ++p) s += A.SQP2[(size_t)p * MROWS + r0 + u];
    sq2[u] = s;
  }
  // QK^T: full 128x128, no-LDS frag loads
  f4 acc[4][4] = {};
#pragma unroll
  for (int ks = 0; ks < 8; ++ks) {
    bfrag a[4], bv[4];
#pragma unroll
    for (int mi = 0; mi < 4; ++mi)
      a[mi] = gfrag(A.H1, DD, r0 + wm * 64 + mi * 16 + fr, ks * 32 + fq * 8);
#pragma unroll
    for (int nj = 0; nj < 4; ++nj)
      bv[nj] = gfrag(A.H2, DD, r0 + wn * 64 + nj * 16 + fr, ks * 32 + fq * 8);
#pragma unroll
    for (int mi = 0; mi < 4; ++mi)
#pragma unroll
      for (int nj = 0; nj < 4; ++nj) acc[mi][nj] = MFMA_B16(a[mi], bv[nj], acc[mi][nj]);
  }
  __syncthreads();  // sqs visible
  float rp[4][4] = {}, cp[4] = {};
#pragma unroll
  for (int nj = 0; nj < 4; ++nj) {
    const int n = wn * 64 + nj * 16 + fr;
    const float s2 = sq2[n];
#pragma unroll
    for (int mi = 0; mi < 4; ++mi) {
      const int m = wm * 64 + mi * 16 + fq * 4;
#pragma unroll
      for (int r = 0; r < 4; ++r) {
        const float d = sq1[m + r] + s2 - 2.f * acc[mi][nj][r];
        const float e = __expf(1.f / (1.f + d));
        acc[mi][nj][r] = e;
        rp[mi][r] += e;
        cp[nj] += e;
      }
    }
  }
#pragma unroll
  for (int mi = 0; mi < 4; ++mi)
#pragma unroll
    for (int r = 0; r < 4; ++r) {
      float v = rp[mi][r];
      v += __shfl_xor(v, 1, 64); v += __shfl_xor(v, 2, 64);
      v += __shfl_xor(v, 4, 64); v += __shfl_xor(v, 8, 64);
      rp[mi][r] = v;
    }
#pragma unroll
  for (int nj = 0; nj < 4; ++nj) {
    float v = cp[nj];
    v += __shfl_xor(v, 16, 64); v += __shfl_xor(v, 32, 64);
    cp[nj] = v;
  }
  if (fr == 0)
#pragma unroll
    for (int mi = 0; mi < 4; ++mi)
#pragma unroll
      for (int r = 0; r < 4; ++r)
        rowp[wn * 128 + wm * 64 + mi * 16 + fq * 4 + r] = rp[mi][r];
  if (fq == 0)
#pragma unroll
    for (int nj = 0; nj < 4; ++nj)
      colp[wm * 128 + wn * 64 + nj * 16 + fr] = cp[nj];
  __syncthreads();
  if (side == 0) {  // row-normalized Ê
#pragma unroll
    for (int nj = 0; nj < 4; ++nj) {
      const int n = wn * 64 + nj * 16 + fr;
#pragma unroll
      for (int mi = 0; mi < 4; ++mi) {
        const int m = wm * 64 + mi * 16 + fq * 4;
#pragma unroll
        for (int r = 0; r < 4; ++r) {
          const float riv = 1.f / (rowp[m + r] + rowp[128 + m + r]);
          *(u16*)((char*)Elds + eswz(m + r, n * 2)) = f2bf(acc[mi][nj][r] * riv);
        }
      }
    }
  } else {  // col-normalized Ê^T
#pragma unroll
    for (int nj = 0; nj < 4; ++nj) {
      const int n = wn * 64 + nj * 16 + fr;
      const float civ = 1.f / (colp[n] + colp[128 + n]);
#pragma unroll
      for (int mi = 0; mi < 4; ++mi) {
        const int m = wm * 64 + mi * 16 + fq * 4;
        us4 pk;
#pragma unroll
        for (int r = 0; r < 4; ++r) pk[r] = f2bf(acc[mi][nj][r] * civ);
        *(us4*)((char*)Elds + eswz(n, m * 2)) = pk;
      }
    }
  }
  __syncthreads();
  // PV: O = Ê @ H (B-frags from HT rows = H columns), this block's 128-col half
  const u16* HT = side ? A.HT1 : A.HT2;
  f4 pv[4][4] = {};
#pragma unroll
  for (int ks = 0; ks < 4; ++ks) {
    bfrag a[4], bv[4];
#pragma unroll
    for (int mi = 0; mi < 4; ++mi)
      a[mi] = ldsE(Elds, wm * 64 + mi * 16 + fr, ks * 64 + fq * 16);
#pragma unroll
    for (int nj = 0; nj < 4; ++nj)
      bv[nj] = gfrag(HT, LL, b * DD + nh * 128 + wn * 64 + nj * 16 + fr, ks * 32 + fq * 8);
#pragma unroll
    for (int mi = 0; mi < 4; ++mi)
#pragma unroll
      for (int nj = 0; nj < 4; ++nj) pv[mi][nj] = MFMA_B16(a[mi], bv[nj], pv[mi][nj]);
  }
  u16* O = side ? A.ALPHA : A.BETA;
#pragma unroll
  for (int nj = 0; nj < 4; ++nj) {
    const int n = nh * 128 + wn * 64 + nj * 16 + fr;
#pragma unroll
    for (int mi = 0; mi < 4; ++mi) {
      const int m = wm * 64 + mi * 16 + fq * 4;
#pragma unroll
      for (int r = 0; r < 4; ++r)
        O[(size_t)(r0 + m + r) * DD + n] = f2bf(pv[mi][nj][r]);
    }
  }
}

// ---------------- vg no-LDS: fused W2 || Wg + gate update ----------------
__device__ void phase_vg(const MArgs& A, int layer, int blk, int t) {
  const int side = blk >> 8;
  const int rem = blk & 255;
  const int m0 = (rem >> 2) * 128;
  const int n0 = (rem & 3) * 64;
  const u16* H = side ? A.H2 : A.H1;
  const u16* CC = side ? A.ALPHA : A.BETA;
  u16* Xo = side ? A.X2 : A.X1;
  const u16* Wt2L = A.Wt2 + (size_t)layer * 131072;
  const u16* WtgL = A.Wtg + (size_t)layer * 65536;
  const float* b2v = A.b2 + layer * DD;
  const float* g2v = A.bn2g + layer * DD;
  const float* be2v = A.bn2b + layer * DD;
  const float* bgv = A.bg + layer * DD;
  const int lane = t & 63, w = t >> 6;
  const int wm = w >> 1, wn = w & 1;
  const int fr = lane & 15, fq = lane >> 4;
  f4 accv[4][2] = {}, accg[4][2] = {};
#pragma unroll
  for (int ks = 0; ks < 8; ++ks) {  // A=H: W2 first half + Wg
    bfrag a[4], b2f[2], bgf[2];
#pragma unroll
    for (int mi = 0; mi < 4; ++mi)
      a[mi] = gfrag(H, DD, m0 + wm * 64 + mi * 16 + fr, ks * 32 + fq * 8);
#pragma unroll
    for (int nj = 0; nj < 2; ++nj) {
      b2f[nj] = gfrag(Wt2L, 2 * DD, n0 + wn * 32 + nj * 16 + fr, ks * 32 + fq * 8);
      bgf[nj] = gfrag(WtgL, DD, n0 + wn * 32 + nj * 16 + fr, ks * 32 + fq * 8);
    }
#pragma unroll
    for (int mi = 0; mi < 4; ++mi)
#pragma unroll
      for (int nj = 0; nj < 2; ++nj) {
        accv[mi][nj] = MFMA_B16(a[mi], b2f[nj], accv[mi][nj]);
        accg[mi][nj] = MFMA_B16(a[mi], bgf[nj], accg[mi][nj]);
      }
  }
#pragma unroll
  for (int ks = 0; ks < 8; ++ks) {  // A=CC: W2 second half
    bfrag a[4], b2f[2];
#pragma unroll
    for (int mi = 0; mi < 4; ++mi)
      a[mi] = gfrag(CC, DD, m0 + wm * 64 + mi * 16 + fr, ks * 32 + fq * 8);
#pragma unroll
    for (int nj = 0; nj < 2; ++nj)
      b2f[nj] = gfrag(Wt2L, 2 * DD, n0 + wn * 32 + nj * 16 + fr, DD + ks * 32 + fq * 8);
#pragma unroll
    for (int mi = 0; mi < 4; ++mi)
#pragma unroll
      for (int nj = 0; nj < 2; ++nj) accv[mi][nj] = MFMA_B16(a[mi], b2f[nj], accv[mi][nj]);
  }
#pragma unroll
  for (int nj = 0; nj < 2; ++nj) {
    const int n = n0 + wn * 32 + nj * 16 + fr;
    const float sc = g2v[n] * BN_SC, bi = b2v[n], be = be2v[n], bgn = bgv[n];
#pragma unroll
    for (int mi = 0; mi < 4; ++mi) {
      const int m = m0 + wm * 64 + mi * 16 + fq * 4;
#pragma unroll
      for (int r = 0; r < 4; ++r) {
        const float v = fmaxf(sc * (accv[mi][nj][r] + bi) + be, 0.f);
        const float g = 1.f / (1.f + __expf(-(accg[mi][nj][r] + bgn)));
        const float h = bf2f(H[(size_t)(m + r) * DD + n]);
        Xo[(size_t)(m + r) * DD + n] = f2bf(v * g + h * (1.f - g));
      }
    }
  }
}

// ---------------- pool -> bf16 hi/lo [128 rows][1024], pad rows zeroed ---
__device__ void phase_pool(const MArgs& A, int b, int d) {
  const u16* x1 = A.X1 + (size_t)b * LL * DD;
  const u16* x2 = A.X2 + (size_t)b * LL * DD;
  float mx1 = -1e30f, s1 = 0.f, mx2 = -1e30f, s2 = 0.f;
  for (int i = 0; i < LL; ++i) {
    const float v1 = bf2f(x1[(size_t)i * DD + d]);
    mx1 = fmaxf(mx1, v1); s1 += v1;
    const float v2 = bf2f(x2[(size_t)i * DD + d]);
    mx2 = fmaxf(mx2, v2); s2 += v2;
  }
  const float vals[4] = {mx1, mx2, s1, s2};
#pragma unroll
  for (int q = 0; q < 4; ++q) {
    const float v = vals[q];
    const u16 h = f2bf(v);
    A.VPh[(size_t)b * 1024 + q * 256 + d] = h;
    A.VPl[(size_t)b * 1024 + q * 256 + d] = f2bf(v - bf2f(h));
  }
  for (int j = d; j < 1024; j += 256) {
    A.VPh[(size_t)(64 + b) * 1024 + j] = 0;
    A.VPl[(size_t)(64 + b) * 1024 + j] = 0;
  }
}

// ---------------- MLP split-K no-LDS ------------------------------------
__device__ void phase_mlp(const u16* __restrict__ Ah, const u16* __restrict__ Al,
                          const u16* __restrict__ Wt, float* __restrict__ PART,
                          int blk, int t) {
  const int n0 = (blk & 7) * 128;
  const int kslice = blk >> 3;
  const int k0 = kslice * 128;
  const int lane = t & 63, w = t >> 6;
  const int wm = w >> 1, wn = w & 1;
  const int fr = lane & 15, fq = lane >> 4;
  f4 acc[4][4] = {};
#pragma unroll
  for (int ks = 0; ks < 4; ++ks) {
    bfrag ah[4], al[4], bv[4];
#pragma unroll
    for (int mi = 0; mi < 4; ++mi) {
      ah[mi] = gfrag(Ah, 1024, wm * 64 + mi * 16 + fr, k0 + ks * 32 + fq * 8);
      al[mi] = gfrag(Al, 1024, wm * 64 + mi * 16 + fr, k0 + ks * 32 + fq * 8);
    }
#pragma unroll
    for (int nj = 0; nj < 4; ++nj)
      bv[nj] = gfrag(Wt, 1024, n0 + wn * 64 + nj * 16 + fr, k0 + ks * 32 + fq * 8);
#pragma unroll
    for (int mi = 0; mi < 4; ++mi)
#pragma unroll
      for (int nj = 0; nj < 4; ++nj) {
        acc[mi][nj] = MFMA_B16(ah[mi], bv[nj], acc[mi][nj]);
        acc[mi][nj] = MFMA_B16(al[mi], bv[nj], acc[mi][nj]);
      }
  }
#pragma unroll
  for (int nj = 0; nj < 4; ++nj) {
    const int n = n0 + wn * 64 + nj * 16 + fr;
#pragma unroll
    for (int mi = 0; mi < 4; ++mi) {
      const int m = wm * 64 + mi * 16 + fq * 4;
#pragma unroll
      for (int r = 0; r < 4; ++r)
        PART[((size_t)kslice * 128 + m + r) * 1024 + n] = acc[mi][nj][r];
    }
  }
}

// combine 8 partials + bias + relu -> hi/lo bf16 (or fp32)
__device__ void phase_comb(const float* __restrict__ P, const float* __restrict__ bias,
                           u16* __restrict__ Oh, u16* __restrict__ Ol,
                           float* __restrict__ Of, int blk, int t) {
#pragma unroll
  for (int e = 0; e < 8; ++e) {
    const int idx = blk * 2048 + e * 256 + t;
    const int col = idx & 1023;
    float s = bias[col];
#pragma unroll
    for (int p = 0; p < 8; ++p) s += P[(size_t)p * 131072 + idx];
    s = fmaxf(s, 0.f);
    if (Oh) {
      const u16 h = f2bf(s);
      Oh[idx] = h;
      Ol[idx] = f2bf(s - bf2f(h));
    } else {
      Of[idx] = s;
    }
  }
}

__device__ void phase_out(const MArgs& A, int b, int t, char* smem) {
  float (*red)[256] = (float(*)[256])smem;
  float a0 = 0.f, a1 = 0.f, a2 = 0.f;
  for (int k = t; k < 1024; k += 256) {
    const float x = A.T2f[(size_t)b * 1024 + k];
    a0 = fmaf(x, A.Wout[k * 3 + 0], a0);
    a1 = fmaf(x, A.Wout[k * 3 + 1], a1);
    a2 = fmaf(x, A.Wout[k * 3 + 2], a2);
  }
  __syncthreads();
  red[0][t] = a0; red[1][t] = a1; red[2][t] = a2;
  __syncthreads();
  for (int off = 128; off > 0; off >>= 1) {
    if (t < off) {
      red[0][t] += red[0][t + off];
      red[1][t] += red[1][t + off];
      red[2][t] += red[2][t + off];
    }
    __syncthreads();
  }
  if (t < 3) A.outp[b * 3 + t] = red[t][0] + A.bout[t];
}

// =================== cooperative mega-kernel (grid-size agnostic) =========
__global__ __launch_bounds__(256, 2) void mega(MArgs A, int nblk) {
  cg::grid_group grid = cg::this_grid();
  __shared__ __align__(16) char smem[SMEM_BYTES];
  const int blk0 = blockIdx.x;
  const int t = threadIdx.x;

  prologue(A, blk0, nblk, t, smem);
  grid.sync();

  for (int i = 0; i < NLAYERS; ++i) {
    for (int task = blk0; task < 512; task += nblk) phase_lbr(A, i, task, t);
    grid.sync();
    for (int task = blk0; task < 256; task += nblk) phase_att(A, task, t, smem);
    grid.sync();
    for (int task = blk0; task < 512; task += nblk) phase_vg(A, i, task, t);
    grid.sync();
  }

  for (int task = blk0; task < 64; task += nblk) phase_pool(A, task, t);
  grid.sync();
  for (int task = blk0; task < 64; task += nblk)
    phase_mlp(A.VPh, A.VPl, A.Wf1t, A.PART1, task, t);
  grid.sync();
  for (int task = blk0; task < 64; task += nblk)
    phase_comb(A.PART1, A.bf1, A.T1h, A.T1l, nullptr, task, t);
  grid.sync();
  for (int task = blk0; task < 64; task += nblk)
    phase_mlp(A.T1h, A.T1l, A.Wf2t, A.PART2, task, t);
  grid.sync();
  for (int task = blk0; task < 64; task += nblk)
    phase_comb(A.PART2, A.bf2, nullptr, nullptr, A.T2f, task, t);
  grid.sync();
  for (int task = blk0; task < 64; task += nblk) phase_out(A, task, t, smem);
}

// =================== regular-launch fallback wrappers =====================
__global__ __launch_bounds__(256) void k_prep(MArgs A) {
  __shared__ __align__(16) char smem[SMEM_BYTES];
  prologue(A, blockIdx.x, gridDim.x, threadIdx.x, smem);
}
__global__ __launch_bounds__(256) void k_lbr(MArgs A, int layer) {
  phase_lbr(A, layer, blockIdx.x, threadIdx.x);
}
__global__ __launch_bounds__(256) void k_att(MArgs A) {
  __shared__ __align__(16) char smem[SMEM_BYTES];
  phase_att(A, blockIdx.x, threadIdx.x, smem);
}
__global__ __launch_bounds__(256) void k_vg(MArgs A, int layer) {
  phase_vg(A, layer, blockIdx.x, threadIdx.x);
}
__global__ __launch_bounds__(256) void k_pool(MArgs A) {
  phase_pool(A, blockIdx.x, threadIdx.x);
}
__global__ __launch_bounds__(256) void k_mlp(MArgs A, int which) {
  if (which == 0) phase_mlp(A.VPh, A.VPl, A.Wf1t, A.PART1, blockIdx.x, threadIdx.x);
  else            phase_mlp(A.T1h, A.T1l, A.Wf2t, A.PART2, blockIdx.x, threadIdx.x);
}
__global__ __launch_bounds__(256) void k_comb(MArgs A, int which) {
  if (which == 0) phase_comb(A.PART1, A.bf1, A.T1h, A.T1l, nullptr, blockIdx.x, threadIdx.x);
  else            phase_comb(A.PART2, A.bf2, nullptr, nullptr, A.T2f, blockIdx.x, threadIdx.x);
}
__global__ __launch_bounds__(256) void k_out(MArgs A) {
  __shared__ __align__(16) char smem[3 * 256 * 4];
  phase_out(A, blockIdx.x, threadIdx.x, smem);
}

extern "C" void kernel_launch(void* const* d_in, const int* in_sizes, int n_in,
                              void* d_out, int out_size, void* d_ws, size_t ws_size,
                              hipStream_t stream) {
  (void)in_sizes; (void)n_in; (void)out_size; (void)ws_size;
  char* wsp = (char*)d_ws;
  auto alloc = [&](size_t bytes) {
    char* p = wsp;
    wsp += (bytes + 255) & ~(size_t)255;
    return p;
  };
  MArgs A;
  A.embed = (const float*)d_in[0];
  A.W1f   = (const float*)d_in[1];
  A.W1r   = (const float*)d_in[2];
  A.b1    = (const float*)d_in[3];
  A.bn1g  = (const float*)d_in[4];
  A.bn1b  = (const float*)d_in[5];
  A.W2    = (const float*)d_in[6];
  A.b2    = (const float*)d_in[7];
  A.bn2g  = (const float*)d_in[8];
  A.bn2b  = (const float*)d_in[9];
  A.Wg    = (const float*)d_in[10];
  A.bg    = (const float*)d_in[11];
  A.Wf1   = (const float*)d_in[12];
  A.bf1   = (const float*)d_in[13];
  A.Wf2   = (const float*)d_in[14];
  A.bf2   = (const float*)d_in[15];
  A.Wout  = (const float*)d_in[16];
  A.bout  = (const float*)d_in[17];
  A.ids1  = (const int*)d_in[18];
  A.ids2  = (const int*)d_in[19];

  A.H1    = (u16*)alloc((size_t)MROWS * DD * 2);
  A.H2    = (u16*)alloc((size_t)MROWS * DD * 2);
  A.HT1   = (u16*)alloc((size_t)MROWS * DD * 2);
  A.HT2   = (u16*)alloc((size_t)MROWS * DD * 2);
  A.X1    = (u16*)alloc((size_t)MROWS * 320 * 2);
  A.X2    = (u16*)alloc((size_t)MROWS * 320 * 2);
  A.BETA  = (u16*)alloc((size_t)MROWS * DD * 2);
  A.ALPHA = (u16*)alloc((size_t)MROWS * DD * 2);
  A.SQP1  = (float*)alloc((size_t)8 * MROWS * 4);
  A.SQP2  = (float*)alloc((size_t)8 * MROWS * 4);
  A.Wt1f  = (u16*)alloc((size_t)DD * 320 * 2);
  A.Wt1r  = (u16*)alloc((size_t)9 * DD * DD * 2);
  A.Wt2   = (u16*)alloc((size_t)10 * DD * 2 * DD * 2);
  A.Wtg   = (u16*)alloc((size_t)10 * DD * DD * 2);
  A.Wf1t  = (u16*)alloc((size_t)1024 * 1024 * 2);
  A.Wf2t  = (u16*)alloc((size_t)1024 * 1024 * 2);
  A.VPh   = (u16*)alloc((size_t)128 * 1024 * 2);
  A.VPl   = (u16*)alloc((size_t)128 * 1024 * 2);
  A.T1h   = (u16*)alloc((size_t)128 * 1024 * 2);
  A.T1l   = (u16*)alloc((size_t)128 * 1024 * 2);
  A.T2f   = (float*)alloc((size_t)128 * 1024 * 4);
  A.PART1 = (float*)alloc((size_t)8 * 128 * 1024 * 4);
  A.PART2 = (float*)alloc((size_t)8 * 128 * 1024 * 4);
  A.outp  = (float*)d_out;

  // size the cooperative grid to what the HW can actually co-schedule
  int dev = 0;
  (void)hipGetDevice(&dev);
  int nCU = 256;
  (void)hipDeviceGetAttribute(&nCU, hipDeviceAttributeMultiprocessorCount, dev);
  int maxAct = 0;
  hipError_t eo = hipOccupancyMaxActiveBlocksPerMultiprocessor(&maxAct, mega, 256, 0);
  int nblk = 512;
  if (eo == hipSuccess && maxAct > 0) {
    nblk = maxAct * nCU;
    if (nblk > 512) nblk = 512;
  }

  void* kargs[] = { &A, &nblk };
  hipError_t err = hipLaunchCooperativeKernel((const void*)mega, dim3(nblk), dim3(256),
                                              kargs, 0, stream);
  if (err != hipSuccess) {
    // regular-launch fallback (identical math, round-5 structure)
    k_prep<<<512, 256, 0, stream>>>(A);
    for (int i = 0; i < NLAYERS; ++i) {
      k_lbr<<<512, 256, 0, stream>>>(A, i);
      k_att<<<256, 256, 0, stream>>>(A);
      k_vg<<<512, 256, 0, stream>>>(A, i);
    }
    k_pool<<<64, 256, 0, stream>>>(A);
    k_mlp<<<64, 256, 0, stream>>>(A, 0);
    k_comb<<<64, 256, 0, stream>>>(A, 0);
    k_mlp<<<64, 256, 0, stream>>>(A, 1);
    k_comb<<<64, 256, 0, stream>>>(A, 1);
    k_out<<<64, 256, 0, stream>>>(A);
  }
}

// Round 9
// 607.162 us; speedup vs baseline: 3.4493x; 3.4493x over previous
//
#include <hip/hip_runtime.h>
#include <hip/hip_bf16.h>
#include <cstddef>

// Problem constants
#define NB 64      // batch
#define LL 128     // L1 == L2
#define EE 300     // embed dim
#define DD 256     // hidden dim
#define NLAYERS 10
#define MROWS (NB * LL)  // 8192

static constexpr float BN_SC = 0.9995003746877562f;  // 1/sqrt(1+1e-3)

typedef unsigned short u16;
typedef __attribute__((ext_vector_type(4))) unsigned short us4;
typedef __attribute__((ext_vector_type(8))) unsigned short us8;
typedef __attribute__((ext_vector_type(8))) short bfrag;   // 8 bf16 (4 VGPR)
typedef __attribute__((ext_vector_type(4))) float f4;      // MFMA C/D

#define MFMA_B16(a, b, c) __builtin_amdgcn_mfma_f32_16x16x32_bf16(a, b, c, 0, 0, 0)

__device__ __forceinline__ u16 f2bf(float x) {
  union { float f; unsigned u; } v; v.f = x;
  unsigned r = v.u + 0x7FFFu + ((v.u >> 16) & 1u);  // RNE
  return (u16)(r >> 16);
}
__device__ __forceinline__ float bf2f(u16 s) {
  union { unsigned u; float f; } v; v.u = (unsigned)s << 16;
  return v.f;
}
__device__ __forceinline__ float4 ld4(const float* p) { return *(const float4*)p; }

// ---------------- async global->LDS staging (16B/lane) -------------------
__device__ __forceinline__ void async16(void* lds, const void* g) {
  __builtin_amdgcn_global_load_lds(
      (const __attribute__((address_space(1))) unsigned int*)g,
      (__attribute__((address_space(3))) unsigned int*)lds, 16, 0, 0);
}

// Stage a [128 rows][32 k] bf16 tile (8KB), 256 threads, 2 async16/thread.
__device__ __forceinline__ void stage_tile(const u16* __restrict__ src, int ld,
                                           int r0, int k0, u16* lds, int t) {
  const int w = t >> 6;
  int c = w * 64 + (t & 63);
  async16((char*)lds + w * 1024,
          src + (size_t)(r0 + (c >> 2)) * ld + k0 + (c & 3) * 8);
  c += 256;
  async16((char*)lds + 4096 + w * 1024,
          src + (size_t)(r0 + (c >> 2)) * ld + k0 + (c & 3) * 8);
}

// One BK=32 step: 8 ds_read_b128 + 16 MFMA per wave (2x2 wave grid).
__device__ __forceinline__ void mfma_step(const u16* As, const u16* Bs, int wm,
                                          int wn, int fr, int fq, f4 acc[4][4]) {
  bfrag a[4], b[4];
#pragma unroll
  for (int i = 0; i < 4; ++i)
    a[i] = *(const bfrag*)&As[(wm * 64 + i * 16 + fr) * 32 + fq * 8];
#pragma unroll
  for (int j = 0; j < 4; ++j)
    b[j] = *(const bfrag*)&Bs[(wn * 64 + j * 16 + fr) * 32 + fq * 8];
#pragma unroll
  for (int i = 0; i < 4; ++i)
#pragma unroll
    for (int j = 0; j < 4; ++j) acc[i][j] = MFMA_B16(a[i], b[j], acc[i][j]);
}

__device__ __forceinline__ void mfma_step2(const u16* As, const u16* B2s,
                                           const u16* Bgs, int wm, int wn,
                                           int fr, int fq, f4 accv[4][4],
                                           f4 accg[4][4]) {
  bfrag a[4], b2[4], bg[4];
#pragma unroll
  for (int i = 0; i < 4; ++i)
    a[i] = *(const bfrag*)&As[(wm * 64 + i * 16 + fr) * 32 + fq * 8];
#pragma unroll
  for (int j = 0; j < 4; ++j) {
    b2[j] = *(const bfrag*)&B2s[(wn * 64 + j * 16 + fr) * 32 + fq * 8];
    bg[j] = *(const bfrag*)&Bgs[(wn * 64 + j * 16 + fr) * 32 + fq * 8];
  }
#pragma unroll
  for (int i = 0; i < 4; ++i)
#pragma unroll
    for (int j = 0; j < 4; ++j) {
      accv[i][j] = MFMA_B16(a[i], b2[j], accv[i][j]);
      accg[i][j] = MFMA_B16(a[i], bg[j], accg[i][j]);
    }
}

// direct MFMA fragment load from row-major [row][k] bf16 global (L2-hot)
__device__ __forceinline__ bfrag gfrag(const u16* __restrict__ p, int ld, int row, int k) {
  return *(const bfrag*)(p + (size_t)row * ld + k);
}

// swizzled byte offset into a [128][128] bf16 LDS matrix (conflict-free b128 reads)
__device__ __forceinline__ int eswz(int row, int colbyte) {
  return (row * 256 + colbyte) ^ ((row & 7) << 4);
}
__device__ __forceinline__ bfrag ldsE(const u16* E, int row, int colbyte) {
  return *(const bfrag*)((const char*)E + eswz(row, colbyte));
}

// ---------------- fused prologue: all weight transposes + gather ---------
__device__ void txw_tile(const float* __restrict__ src, u16* __restrict__ dst,
                         int K, int N, int Kpad, int k0, int n0, int t,
                         float (*tileS)[65]) {
  __syncthreads();  // protect LDS across task iterations
  {
    const int kr = t >> 2, nc = (t & 3) * 16;
    const int k = k0 + kr;
#pragma unroll
    for (int j = 0; j < 16; j += 4) {
      float4 v = (k < K) ? ld4(src + (size_t)k * N + n0 + nc + j)
                         : make_float4(0.f, 0.f, 0.f, 0.f);
      tileS[kr][nc + j + 0] = v.x; tileS[kr][nc + j + 1] = v.y;
      tileS[kr][nc + j + 2] = v.z; tileS[kr][nc + j + 3] = v.w;
    }
  }
  __syncthreads();
  {
    const int nr = t >> 2, kc = (t & 3) * 16;
    us8 o0, o1;
#pragma unroll
    for (int j = 0; j < 8; ++j) {
      o0[j] = f2bf(tileS[kc + j][nr]);
      o1[j] = f2bf(tileS[kc + 8 + j][nr]);
    }
    u16* d = dst + (size_t)(n0 + nr) * Kpad + k0 + kc;
    *(us8*)d = o0;
    *(us8*)(d + 8) = o1;
  }
}

__global__ __launch_bounds__(256)
void k_prep(const float* __restrict__ W1f, const float* __restrict__ W1r,
            const float* __restrict__ W2, const float* __restrict__ Wg,
            const float* __restrict__ Wf1, const float* __restrict__ Wf2,
            u16* __restrict__ Wt1f, u16* __restrict__ Wt1r,
            u16* __restrict__ Wt2, u16* __restrict__ Wtg,
            u16* __restrict__ Wf1t, u16* __restrict__ Wf2t,
            const float* __restrict__ embed, const int* __restrict__ ids1,
            const int* __restrict__ ids2, u16* __restrict__ X1,
            u16* __restrict__ X2) {
  __shared__ float tileS[64][65];
  const int t = threadIdx.x;
  const int blk = blockIdx.x, nblk = gridDim.x;
  for (int it = blk; it < 20; it += nblk)
    txw_tile(W1f, Wt1f, 300, 256, 320, (it % 5) * 64, (it / 5) * 64, t, tileS);
  for (int it = blk; it < 144; it += nblk) {
    const int l = it / 16, r = it % 16;
    txw_tile(W1r + (size_t)l * 65536, Wt1r + (size_t)l * 65536, 256, 256, 256,
             (r % 4) * 64, (r / 4) * 64, t, tileS);
  }
  for (int it = blk; it < 320; it += nblk) {
    const int l = it / 32, r = it % 32;
    txw_tile(W2 + (size_t)l * 131072, Wt2 + (size_t)l * 131072, 512, 256, 512,
             (r % 8) * 64, (r / 8) * 64, t, tileS);
  }
  for (int it = blk; it < 160; it += nblk) {
    const int l = it / 16, r = it % 16;
    txw_tile(Wg + (size_t)l * 65536, Wtg + (size_t)l * 65536, 256, 256, 256,
             (r % 4) * 64, (r / 4) * 64, t, tileS);
  }
  for (int it = blk; it < 256; it += nblk)
    txw_tile(Wf1, Wf1t, 1024, 1024, 1024, (it % 16) * 64, (it / 16) * 64, t, tileS);
  for (int it = blk; it < 256; it += nblk)
    txw_tile(Wf2, Wf2t, 1024, 1024, 1024, (it % 16) * 64, (it / 16) * 64, t, tileS);
  for (int g = blk; g < 4096; g += nblk) {
    const int side = g & 1;
    const int* ids = side ? ids2 : ids1;
    u16* E = side ? X2 : X1;
    const int row = (g >> 1) * 4 + (t >> 6);
    const int lane = t & 63;
    const float* src = embed + (size_t)ids[row] * EE;
    u16* dst = E + (size_t)row * 320;
#pragma unroll
    for (int j = 0; j < 5; ++j) {
      const int c = lane + 64 * j;
      dst[c] = f2bf(c < EE ? src[c] : 0.f);
    }
  }
}

// ---------------- LBR-1 (LDS dbuf, +H^T epilogue, +sq-norm partials) -----
__global__ __launch_bounds__(256)
void mfma_lbr(const u16* __restrict__ A0, const u16* __restrict__ A1, int lda,
              int K, const u16* __restrict__ Wt, const float* __restrict__ bias,
              const float* __restrict__ gam, const float* __restrict__ bet,
              u16* __restrict__ O0, u16* __restrict__ O1,
              u16* __restrict__ HTa, u16* __restrict__ HTb,
              float* __restrict__ SQPa, float* __restrict__ SQPb) {
  const int side = blockIdx.z;
  const u16* A = side ? A1 : A0;
  u16* O = side ? O1 : O0;
  u16* HT = side ? HTb : HTa;
  float* SQP = side ? SQPb : SQPa;
  __shared__ u16 As[2][4096], Bs[2][4096];
  const int t = threadIdx.x;
  const int m0 = blockIdx.x * 128, n0 = blockIdx.y * 128;
  const int lane = t & 63, w = t >> 6, wm = w >> 1, wn = w & 1;
  const int fr = lane & 15, fq = lane >> 4;
  f4 acc[4][4] = {};
  const int nt = K / 32;
  stage_tile(A, lda, m0, 0, As[0], t);
  stage_tile(Wt, K, n0, 0, Bs[0], t);
  __syncthreads();
  for (int ks = 0; ks < nt; ++ks) {
    const int cur = ks & 1;
    if (ks + 1 < nt) {
      stage_tile(A, lda, m0, (ks + 1) * 32, As[cur ^ 1], t);
      stage_tile(Wt, K, n0, (ks + 1) * 32, Bs[cur ^ 1], t);
    }
    mfma_step(As[cur], Bs[cur], wm, wn, fr, fq, acc);
    __syncthreads();
  }
  const int b = m0 >> 7;
  float rsq[4][4] = {};
#pragma unroll
  for (int nj = 0; nj < 4; ++nj) {
    const int n = n0 + wn * 64 + nj * 16 + fr;
    const float sc = gam[n] * BN_SC, bi = bias[n], be = bet[n];
#pragma unroll
    for (int mi = 0; mi < 4; ++mi) {
      const int m = m0 + wm * 64 + mi * 16 + fq * 4;
      us4 pk;
#pragma unroll
      for (int r = 0; r < 4; ++r) {
        const float x = sc * (acc[mi][nj][r] + bi) + be;
        const u16 hb = f2bf(fmaxf(x, 0.f));
        O[(size_t)(m + r) * DD + n] = hb;
        pk[r] = hb;
        const float h = bf2f(hb);  // norms must match stored bf16 H
        rsq[mi][r] += h * h;
      }
      *(us4*)&HT[((size_t)b * DD + n) * LL + (m & 127)] = pk;
    }
  }
#pragma unroll
  for (int mi = 0; mi < 4; ++mi)
#pragma unroll
    for (int r = 0; r < 4; ++r) {
      float v = rsq[mi][r];
      v += __shfl_xor(v, 1, 64); v += __shfl_xor(v, 2, 64);
      v += __shfl_xor(v, 4, 64); v += __shfl_xor(v, 8, 64);
      rsq[mi][r] = v;
    }
  if (fr == 0) {
    const int p = blockIdx.y * 2 + wn;  // 4 partials per row
#pragma unroll
    for (int mi = 0; mi < 4; ++mi)
#pragma unroll
      for (int r = 0; r < 4; ++r)
        SQP[(size_t)p * MROWS + m0 + wm * 64 + mi * 16 + fq * 4 + r] = rsq[mi][r];
  }
}

// ------- fused att+attn per (batch, N-half, side): E in LDS, PV out ------
__global__ __launch_bounds__(256, 2)
void attf(const u16* __restrict__ H1, const u16* __restrict__ H2,
          const float* __restrict__ SQP1, const float* __restrict__ SQP2,
          const u16* __restrict__ HT1, const u16* __restrict__ HT2,
          u16* __restrict__ BETA, u16* __restrict__ ALPHA) {
  const int b = blockIdx.x, nh = blockIdx.y, side = blockIdx.z;
  __shared__ u16 Elds[128 * 128];  // 32KB swizzled (Ê or Ê^T per side)
  __shared__ float sqs[2][128], rowp[2][128], colp[2][128];
  const int t = threadIdx.x, lane = t & 63, w = t >> 6;
  const int wm = w >> 1, wn = w & 1;
  const int fr = lane & 15, fq = lane >> 4;
  const int r0 = b * LL;
  if (t < 128) {
    float s = 0.f;
#pragma unroll
    for (int p = 0; p < 4; ++p) s += SQP1[(size_t)p * MROWS + r0 + t];
    sqs[0][t] = s;
  } else {
    const int u = t - 128;
    float s = 0.f;
#pragma unroll
    for (int p = 0; p < 4; ++p) s += SQP2[(size_t)p * MROWS + r0 + u];
    sqs[1][u] = s;
  }
  // QK^T: full 128x128 E, no-LDS frag loads
  f4 acc[4][4] = {};
#pragma unroll
  for (int ks = 0; ks < 8; ++ks) {
    bfrag a[4], bv[4];
#pragma unroll
    for (int mi = 0; mi < 4; ++mi)
      a[mi] = gfrag(H1, DD, r0 + wm * 64 + mi * 16 + fr, ks * 32 + fq * 8);
#pragma unroll
    for (int nj = 0; nj < 4; ++nj)
      bv[nj] = gfrag(H2, DD, r0 + wn * 64 + nj * 16 + fr, ks * 32 + fq * 8);
#pragma unroll
    for (int mi = 0; mi < 4; ++mi)
#pragma unroll
      for (int nj = 0; nj < 4; ++nj) acc[mi][nj] = MFMA_B16(a[mi], bv[nj], acc[mi][nj]);
  }
  __syncthreads();  // sqs visible
  float rp[4][4] = {}, cp[4] = {};
#pragma unroll
  for (int nj = 0; nj < 4; ++nj) {
    const int n = wn * 64 + nj * 16 + fr;
    const float s2 = sqs[1][n];
#pragma unroll
    for (int mi = 0; mi < 4; ++mi) {
      const int m = wm * 64 + mi * 16 + fq * 4;
#pragma unroll
      for (int r = 0; r < 4; ++r) {
        const float d = sqs[0][m + r] + s2 - 2.f * acc[mi][nj][r];
        const float e = __expf(1.f / (1.f + d));
        acc[mi][nj][r] = e;
        rp[mi][r] += e;
        cp[nj] += e;
      }
    }
  }
#pragma unroll
  for (int mi = 0; mi < 4; ++mi)
#pragma unroll
    for (int r = 0; r < 4; ++r) {
      float v = rp[mi][r];
      v += __shfl_xor(v, 1, 64); v += __shfl_xor(v, 2, 64);
      v += __shfl_xor(v, 4, 64); v += __shfl_xor(v, 8, 64);
      rp[mi][r] = v;
    }
#pragma unroll
  for (int nj = 0; nj < 4; ++nj) {
    float v = cp[nj];
    v += __shfl_xor(v, 16, 64); v += __shfl_xor(v, 32, 64);
    cp[nj] = v;
  }
  if (fr == 0)
#pragma unroll
    for (int mi = 0; mi < 4; ++mi)
#pragma unroll
      for (int r = 0; r < 4; ++r)
        rowp[wn][wm * 64 + mi * 16 + fq * 4 + r] = rp[mi][r];
  if (fq == 0)
#pragma unroll
    for (int nj = 0; nj < 4; ++nj)
      colp[wm][wn * 64 + nj * 16 + fr] = cp[nj];
  __syncthreads();
  if (side == 0) {  // row-normalized Ê
#pragma unroll
    for (int nj = 0; nj < 4; ++nj) {
      const int n = wn * 64 + nj * 16 + fr;
#pragma unroll
      for (int mi = 0; mi < 4; ++mi) {
        const int m = wm * 64 + mi * 16 + fq * 4;
#pragma unroll
        for (int r = 0; r < 4; ++r) {
          const float riv = 1.f / (rowp[0][m + r] + rowp[1][m + r]);
          *(u16*)((char*)Elds + eswz(m + r, n * 2)) = f2bf(acc[mi][nj][r] * riv);
        }
      }
    }
  } else {  // col-normalized Ê^T
#pragma unroll
    for (int nj = 0; nj < 4; ++nj) {
      const int n = wn * 64 + nj * 16 + fr;
      const float civ = 1.f / (colp[0][n] + colp[1][n]);
#pragma unroll
      for (int mi = 0; mi < 4; ++mi) {
        const int m = wm * 64 + mi * 16 + fq * 4;
        us4 pk;
#pragma unroll
        for (int r = 0; r < 4; ++r) pk[r] = f2bf(acc[mi][nj][r] * civ);
        *(us4*)((char*)Elds + eswz(n, m * 2)) = pk;
      }
    }
  }
  __syncthreads();
  // PV: O = Ê @ H (B-frags from HT rows = H columns), this block's 128-col half
  const u16* HT = side ? HT1 : HT2;
  f4 pv[4][4] = {};
#pragma unroll
  for (int ks = 0; ks < 4; ++ks) {
    bfrag a[4], bv[4];
#pragma unroll
    for (int mi = 0; mi < 4; ++mi)
      a[mi] = ldsE(Elds, wm * 64 + mi * 16 + fr, ks * 64 + fq * 16);
#pragma unroll
    for (int nj = 0; nj < 4; ++nj)
      bv[nj] = gfrag(HT, LL, b * DD + nh * 128 + wn * 64 + nj * 16 + fr, ks * 32 + fq * 8);
#pragma unroll
    for (int mi = 0; mi < 4; ++mi)
#pragma unroll
      for (int nj = 0; nj < 4; ++nj) pv[mi][nj] = MFMA_B16(a[mi], bv[nj], pv[mi][nj]);
  }
  u16* O = side ? ALPHA : BETA;
#pragma unroll
  for (int nj = 0; nj < 4; ++nj) {
    const int n = nh * 128 + wn * 64 + nj * 16 + fr;
#pragma unroll
    for (int mi = 0; mi < 4; ++mi) {
      const int m = wm * 64 + mi * 16 + fq * 4;
#pragma unroll
      for (int r = 0; r < 4; ++r)
        O[(size_t)(r0 + m + r) * DD + n] = f2bf(pv[mi][nj][r]);
    }
  }
}

// ---------------- fused W2 || Wg GEMMs + gate update (LDS dbuf) ----------
__global__ __launch_bounds__(256, 1)
void mfma_vg(const u16* __restrict__ Hbf1, const u16* __restrict__ Hbf2,
             const u16* __restrict__ BETA, const u16* __restrict__ ALPHA,
             const u16* __restrict__ Wt2, const u16* __restrict__ Wtg,
             const float* __restrict__ b2, const float* __restrict__ g2,
             const float* __restrict__ be2, const float* __restrict__ bgv,
             u16* __restrict__ X0, u16* __restrict__ X1p) {
  const int side = blockIdx.z;
  const u16* H = side ? Hbf2 : Hbf1;
  const u16* CC = side ? ALPHA : BETA;
  u16* X = side ? X1p : X0;
  const int m0 = blockIdx.x * 128, n0 = blockIdx.y * 128;
  __shared__ u16 As[2][4096], B2s[2][4096], Bgs[2][4096];
  const int t = threadIdx.x;
  const int lane = t & 63, w = t >> 6, wm = w >> 1, wn = w & 1;
  const int fr = lane & 15, fq = lane >> 4;
  f4 accv[4][4] = {}, accg[4][4] = {};
  stage_tile(H, DD, m0, 0, As[0], t);
  stage_tile(Wt2, 2 * DD, n0, 0, B2s[0], t);
  stage_tile(Wtg, DD, n0, 0, Bgs[0], t);
  __syncthreads();
  for (int ks = 0; ks < 16; ++ks) {
    const int cur = ks & 1;
    if (ks + 1 < 16) {
      const u16* Asrc = (ks + 1 < 8) ? H : CC;
      stage_tile(Asrc, DD, m0, ((ks + 1) & 7) * 32, As[cur ^ 1], t);
      stage_tile(Wt2, 2 * DD, n0, (ks + 1) * 32, B2s[cur ^ 1], t);
      if (ks + 1 < 8) stage_tile(Wtg, DD, n0, (ks + 1) * 32, Bgs[cur ^ 1], t);
    }
    if (ks < 8)
      mfma_step2(As[cur], B2s[cur], Bgs[cur], wm, wn, fr, fq, accv, accg);
    else
      mfma_step(As[cur], B2s[cur], wm, wn, fr, fq, accv);
    __syncthreads();
  }
#pragma unroll
  for (int nj = 0; nj < 4; ++nj) {
    const int n = n0 + wn * 64 + nj * 16 + fr;
    const float sc = g2[n] * BN_SC, bi = b2[n], be = be2[n], bgn = bgv[n];
#pragma unroll
    for (int mi = 0; mi < 4; ++mi) {
      const int m = m0 + wm * 64 + mi * 16 + fq * 4;
#pragma unroll
      for (int r = 0; r < 4; ++r) {
        const float v = fmaxf(sc * (accv[mi][nj][r] + bi) + be, 0.f);
        const float g = 1.f / (1.f + __expf(-(accg[mi][nj][r] + bgn)));
        const float h = bf2f(H[(size_t)(m + r) * DD + n]);
        X[(size_t)(m + r) * DD + n] = f2bf(v * g + h * (1.f - g));
      }
    }
  }
}

// ---------------- pool -> bf16 hi/lo [128 rows][1024], pad rows zeroed ---
__global__ __launch_bounds__(256)
void pool_kernel(const u16* __restrict__ X1, const u16* __restrict__ X2,
                 u16* __restrict__ VPh, u16* __restrict__ VPl) {
  const int b = blockIdx.x;
  const int d = threadIdx.x;  // 256
  const u16* x1 = X1 + (size_t)b * LL * DD;
  const u16* x2 = X2 + (size_t)b * LL * DD;
  float mx1 = -1e30f, s1 = 0.f, mx2 = -1e30f, s2 = 0.f;
  for (int i = 0; i < LL; ++i) {
    const float v1 = bf2f(x1[(size_t)i * DD + d]);
    mx1 = fmaxf(mx1, v1); s1 += v1;
    const float v2 = bf2f(x2[(size_t)i * DD + d]);
    mx2 = fmaxf(mx2, v2); s2 += v2;
  }
  const float vals[4] = {mx1, mx2, s1, s2};
#pragma unroll
  for (int q = 0; q < 4; ++q) {
    const float v = vals[q];
    const u16 h = f2bf(v);
    VPh[(size_t)b * 1024 + q * 256 + d] = h;
    VPl[(size_t)b * 1024 + q * 256 + d] = f2bf(v - bf2f(h));
  }
  for (int j = d; j < 1024; j += 256) {
    VPh[(size_t)(64 + b) * 1024 + j] = 0;
    VPl[(size_t)(64 + b) * 1024 + j] = 0;
  }
}

// ---------------- MLP split-K no-LDS: PART[slice] = (Ah+Al) @ Wt-slice ---
__global__ __launch_bounds__(256, 2)
void mlp_sk(const u16* __restrict__ Ah, const u16* __restrict__ Al,
            const u16* __restrict__ Wt, float* __restrict__ PART) {
  const int n0 = blockIdx.x * 128;   // 8 N-blocks
  const int k0 = blockIdx.y * 128;   // 8 K-slices
  const int t = threadIdx.x, lane = t & 63, w = t >> 6;
  const int wm = w >> 1, wn = w & 1;
  const int fr = lane & 15, fq = lane >> 4;
  f4 acc[4][4] = {};
#pragma unroll
  for (int ks = 0; ks < 4; ++ks) {
    bfrag ah[4], al[4], bv[4];
#pragma unroll
    for (int mi = 0; mi < 4; ++mi) {
      ah[mi] = gfrag(Ah, 1024, wm * 64 + mi * 16 + fr, k0 + ks * 32 + fq * 8);
      al[mi] = gfrag(Al, 1024, wm * 64 + mi * 16 + fr, k0 + ks * 32 + fq * 8);
    }
#pragma unroll
    for (int nj = 0; nj < 4; ++nj)
      bv[nj] = gfrag(Wt, 1024, n0 + wn * 64 + nj * 16 + fr, k0 + ks * 32 + fq * 8);
#pragma unroll
    for (int mi = 0; mi < 4; ++mi)
#pragma unroll
      for (int nj = 0; nj < 4; ++nj) {
        acc[mi][nj] = MFMA_B16(ah[mi], bv[nj], acc[mi][nj]);
        acc[mi][nj] = MFMA_B16(al[mi], bv[nj], acc[mi][nj]);
      }
  }
#pragma unroll
  for (int nj = 0; nj < 4; ++nj) {
    const int n = n0 + wn * 64 + nj * 16 + fr;
#pragma unroll
    for (int mi = 0; mi < 4; ++mi) {
      const int m = wm * 64 + mi * 16 + fq * 4;
#pragma unroll
      for (int r = 0; r < 4; ++r)
        PART[((size_t)blockIdx.y * 128 + m + r) * 1024 + n] = acc[mi][nj][r];
    }
  }
}

// combine 8 partials + bias + relu -> hi/lo bf16 (or fp32)
__global__ __launch_bounds__(512)
void mlp_comb(const float* __restrict__ P, const float* __restrict__ bias,
              u16* __restrict__ Oh, u16* __restrict__ Ol,
              float* __restrict__ Of) {
#pragma unroll
  for (int e = 0; e < 8; ++e) {
    const int idx = blockIdx.x * 4096 + e * 512 + threadIdx.x;
    const int col = idx & 1023;
    float s = bias[col];
#pragma unroll
    for (int p = 0; p < 8; ++p) s += P[(size_t)p * 131072 + idx];
    s = fmaxf(s, 0.f);
    if (Oh) {
      const u16 h = f2bf(s);
      Oh[idx] = h;
      Ol[idx] = f2bf(s - bf2f(h));
    } else {
      Of[idx] = s;
    }
  }
}

__global__ __launch_bounds__(256)
void out_kernel(const float* __restrict__ T2, const float* __restrict__ Wout,
                const float* __restrict__ bout, float* __restrict__ out) {
  const int b = blockIdx.x;
  const int t = threadIdx.x;  // 256
  float a0 = 0.f, a1 = 0.f, a2 = 0.f;
  for (int k = t; k < 1024; k += 256) {
    const float x = T2[(size_t)b * 1024 + k];
    a0 = fmaf(x, Wout[k * 3 + 0], a0);
    a1 = fmaf(x, Wout[k * 3 + 1], a1);
    a2 = fmaf(x, Wout[k * 3 + 2], a2);
  }
  __shared__ float red[3][256];
  red[0][t] = a0; red[1][t] = a1; red[2][t] = a2;
  __syncthreads();
  for (int off = 128; off > 0; off >>= 1) {
    if (t < off) {
      red[0][t] += red[0][t + off];
      red[1][t] += red[1][t + off];
      red[2][t] += red[2][t + off];
    }
    __syncthreads();
  }
  if (t < 3) out[b * 3 + t] = red[t][0] + bout[t];
}

extern "C" void kernel_launch(void* const* d_in, const int* in_sizes, int n_in,
                              void* d_out, int out_size, void* d_ws, size_t ws_size,
                              hipStream_t stream) {
  (void)in_sizes; (void)n_in; (void)out_size; (void)ws_size;
  const float* embed = (const float*)d_in[0];
  const float* W1f   = (const float*)d_in[1];
  const float* W1r   = (const float*)d_in[2];
  const float* b1    = (const float*)d_in[3];
  const float* bn1g  = (const float*)d_in[4];
  const float* bn1b  = (const float*)d_in[5];
  const float* W2    = (const float*)d_in[6];
  const float* b2    = (const float*)d_in[7];
  const float* bn2g  = (const float*)d_in[8];
  const float* bn2b  = (const float*)d_in[9];
  const float* Wg    = (const float*)d_in[10];
  const float* bg    = (const float*)d_in[11];
  const float* Wf1   = (const float*)d_in[12];
  const float* bf1   = (const float*)d_in[13];
  const float* Wf2   = (const float*)d_in[14];
  const float* bf2   = (const float*)d_in[15];
  const float* Wout  = (const float*)d_in[16];
  const float* bout  = (const float*)d_in[17];
  const int* ids1    = (const int*)d_in[18];
  const int* ids2    = (const int*)d_in[19];

  char* wsp = (char*)d_ws;
  auto alloc = [&](size_t bytes) {
    char* p = wsp;
    wsp += (bytes + 255) & ~(size_t)255;
    return p;
  };
  u16* Hbf1  = (u16*)alloc((size_t)MROWS * DD * 2);
  u16* Hbf2  = (u16*)alloc((size_t)MROWS * DD * 2);
  u16* HT1   = (u16*)alloc((size_t)MROWS * DD * 2);
  u16* HT2   = (u16*)alloc((size_t)MROWS * DD * 2);
  u16* Xbf1  = (u16*)alloc((size_t)MROWS * 320 * 2);
  u16* Xbf2  = (u16*)alloc((size_t)MROWS * 320 * 2);
  u16* BETAb = (u16*)alloc((size_t)MROWS * DD * 2);
  u16* ALPHAb= (u16*)alloc((size_t)MROWS * DD * 2);
  float* SQP1= (float*)alloc((size_t)4 * MROWS * 4);
  float* SQP2= (float*)alloc((size_t)4 * MROWS * 4);
  u16* Wt1f  = (u16*)alloc((size_t)DD * 320 * 2);
  u16* Wt1r  = (u16*)alloc((size_t)9 * DD * DD * 2);
  u16* Wt2   = (u16*)alloc((size_t)10 * DD * 2 * DD * 2);
  u16* Wtg   = (u16*)alloc((size_t)10 * DD * DD * 2);
  u16* Wf1t  = (u16*)alloc((size_t)1024 * 1024 * 2);
  u16* Wf2t  = (u16*)alloc((size_t)1024 * 1024 * 2);
  u16* VPh   = (u16*)alloc((size_t)128 * 1024 * 2);
  u16* VPl   = (u16*)alloc((size_t)128 * 1024 * 2);
  u16* T1h   = (u16*)alloc((size_t)128 * 1024 * 2);
  u16* T1l   = (u16*)alloc((size_t)128 * 1024 * 2);
  float* T2f = (float*)alloc((size_t)128 * 1024 * 4);
  float* PART1 = (float*)alloc((size_t)8 * 128 * 1024 * 4);
  float* PART2 = (float*)alloc((size_t)8 * 128 * 1024 * 4);

  k_prep<<<512, 256, 0, stream>>>(W1f, W1r, W2, Wg, Wf1, Wf2,
                                  Wt1f, Wt1r, Wt2, Wtg, Wf1t, Wf2t,
                                  embed, ids1, ids2, Xbf1, Xbf2);

  for (int i = 0; i < NLAYERS; ++i) {
    const u16* Wt1 = (i == 0) ? Wt1f : (Wt1r + (size_t)(i - 1) * DD * DD);
    const int K1 = (i == 0) ? 320 : DD;
    mfma_lbr<<<dim3(MROWS / 128, 2, 2), 256, 0, stream>>>(
        Xbf1, Xbf2, K1, K1, Wt1, b1 + i * DD, bn1g + i * DD, bn1b + i * DD,
        Hbf1, Hbf2, HT1, HT2, SQP1, SQP2);
    attf<<<dim3(NB, 2, 2), 256, 0, stream>>>(Hbf1, Hbf2, SQP1, SQP2, HT1, HT2,
                                             BETAb, ALPHAb);
    mfma_vg<<<dim3(MROWS / 128, 2, 2), 256, 0, stream>>>(
        Hbf1, Hbf2, BETAb, ALPHAb, Wt2 + (size_t)i * DD * 2 * DD,
        Wtg + (size_t)i * DD * DD, b2 + i * DD, bn2g + i * DD, bn2b + i * DD,
        bg + i * DD, Xbf1, Xbf2);
  }
  pool_kernel<<<NB, DD, 0, stream>>>(Xbf1, Xbf2, VPh, VPl);
  mlp_sk<<<dim3(8, 8), 256, 0, stream>>>(VPh, VPl, Wf1t, PART1);
  mlp_comb<<<32, 512, 0, stream>>>(PART1, bf1, T1h, T1l, nullptr);
  mlp_sk<<<dim3(8, 8), 256, 0, stream>>>(T1h, T1l, Wf2t, PART2);
  mlp_comb<<<32, 512, 0, stream>>>(PART2, bf2, nullptr, nullptr, T2f);
  out_kernel<<<NB, 256, 0, stream>>>(T2f, Wout, bout, (float*)d_out);
}

// Round 10
// 524.345 us; speedup vs baseline: 3.9941x; 1.1579x over previous
//
#include <hip/hip_runtime.h>
#include <hip/hip_bf16.h>
#include <cstddef>

// Problem constants
#define NB 64      // batch
#define LL 128     // L1 == L2
#define EE 300     // embed dim
#define DD 256     // hidden dim
#define NLAYERS 10
#define MROWS (NB * LL)  // 8192

static constexpr float BN_SC = 0.9995003746877562f;  // 1/sqrt(1+1e-3)

typedef unsigned short u16;
typedef __attribute__((ext_vector_type(4))) unsigned short us4;
typedef __attribute__((ext_vector_type(8))) unsigned short us8;
typedef __attribute__((ext_vector_type(8))) short bfrag;   // 8 bf16 (4 VGPR)
typedef __attribute__((ext_vector_type(4))) float f4;      // MFMA C/D

#define MFMA_B16(a, b, c) __builtin_amdgcn_mfma_f32_16x16x32_bf16(a, b, c, 0, 0, 0)

__device__ __forceinline__ u16 f2bf(float x) {
  union { float f; unsigned u; } v; v.f = x;
  unsigned r = v.u + 0x7FFFu + ((v.u >> 16) & 1u);  // RNE
  return (u16)(r >> 16);
}
__device__ __forceinline__ float bf2f(u16 s) {
  union { unsigned u; float f; } v; v.u = (unsigned)s << 16;
  return v.f;
}
__device__ __forceinline__ float4 ld4(const float* p) { return *(const float4*)p; }

// ---------------- async global->LDS staging (16B/lane) -------------------
__device__ __forceinline__ void async16(void* lds, const void* g) {
  __builtin_amdgcn_global_load_lds(
      (const __attribute__((address_space(1))) unsigned int*)g,
      (__attribute__((address_space(3))) unsigned int*)lds, 16, 0, 0);
}

// Stage a [128 rows][32 k] bf16 tile (8KB), 256 threads, 2 async16/thread.
__device__ __forceinline__ void stage_tile(const u16* __restrict__ src, int ld,
                                           int r0, int k0, u16* lds, int t) {
  const int w = t >> 6;
  int c = w * 64 + (t & 63);
  async16((char*)lds + w * 1024,
          src + (size_t)(r0 + (c >> 2)) * ld + k0 + (c & 3) * 8);
  c += 256;
  async16((char*)lds + 4096 + w * 1024,
          src + (size_t)(r0 + (c >> 2)) * ld + k0 + (c & 3) * 8);
}

// Stage a [64 rows][32 k] bf16 tile (4KB), 256 threads, 1 async16/thread.
__device__ __forceinline__ void stage_tile64(const u16* __restrict__ src, int ld,
                                             int r0, int k0, u16* lds, int t) {
  const int w = t >> 6;
  const int c = t;
  async16((char*)lds + w * 1024,
          src + (size_t)(r0 + (c >> 2)) * ld + k0 + (c & 3) * 8);
}

// 128m x 128n step (2x2 waves): 8 ds_read_b128 + 16 MFMA per wave.
__device__ __forceinline__ void mfma_step(const u16* As, const u16* Bs, int wm,
                                          int wn, int fr, int fq, f4 acc[4][4]) {
  bfrag a[4], b[4];
#pragma unroll
  for (int i = 0; i < 4; ++i)
    a[i] = *(const bfrag*)&As[(wm * 64 + i * 16 + fr) * 32 + fq * 8];
#pragma unroll
  for (int j = 0; j < 4; ++j)
    b[j] = *(const bfrag*)&Bs[(wn * 64 + j * 16 + fr) * 32 + fq * 8];
#pragma unroll
  for (int i = 0; i < 4; ++i)
#pragma unroll
    for (int j = 0; j < 4; ++j) acc[i][j] = MFMA_B16(a[i], b[j], acc[i][j]);
}

// 128m x 64n step (2x2 waves, n-sub 32): 6 reads + 8 MFMA per wave.
__device__ __forceinline__ void mfma_step_n64(const u16* As, const u16* Bs, int wm,
                                              int wn, int fr, int fq, f4 acc[4][2]) {
  bfrag a[4], b[2];
#pragma unroll
  for (int i = 0; i < 4; ++i)
    a[i] = *(const bfrag*)&As[(wm * 64 + i * 16 + fr) * 32 + fq * 8];
#pragma unroll
  for (int j = 0; j < 2; ++j)
    b[j] = *(const bfrag*)&Bs[(wn * 32 + j * 16 + fr) * 32 + fq * 8];
#pragma unroll
  for (int i = 0; i < 4; ++i)
#pragma unroll
    for (int j = 0; j < 2; ++j) acc[i][j] = MFMA_B16(a[i], b[j], acc[i][j]);
}

__device__ __forceinline__ void mfma_step2_n64(const u16* As, const u16* B2s,
                                               const u16* Bgs, int wm, int wn,
                                               int fr, int fq, f4 accv[4][2],
                                               f4 accg[4][2]) {
  bfrag a[4], b2[2], bg[2];
#pragma unroll
  for (int i = 0; i < 4; ++i)
    a[i] = *(const bfrag*)&As[(wm * 64 + i * 16 + fr) * 32 + fq * 8];
#pragma unroll
  for (int j = 0; j < 2; ++j) {
    b2[j] = *(const bfrag*)&B2s[(wn * 32 + j * 16 + fr) * 32 + fq * 8];
    bg[j] = *(const bfrag*)&Bgs[(wn * 32 + j * 16 + fr) * 32 + fq * 8];
  }
#pragma unroll
  for (int i = 0; i < 4; ++i)
#pragma unroll
    for (int j = 0; j < 2; ++j) {
      accv[i][j] = MFMA_B16(a[i], b2[j], accv[i][j]);
      accg[i][j] = MFMA_B16(a[i], bg[j], accg[i][j]);
    }
}

// direct MFMA fragment load from row-major [row][k] bf16 global (L2-hot)
__device__ __forceinline__ bfrag gfrag(const u16* __restrict__ p, int ld, int row, int k) {
  return *(const bfrag*)(p + (size_t)row * ld + k);
}

// swizzled byte offset into a [128][128] bf16 LDS matrix (conflict-free b128 reads)
__device__ __forceinline__ int eswz(int row, int colbyte) {
  return (row * 256 + colbyte) ^ ((row & 7) << 4);
}
__device__ __forceinline__ bfrag ldsE(const u16* E, int row, int colbyte) {
  return *(const bfrag*)((const char*)E + eswz(row, colbyte));
}

// ---------------- fused prologue: weight transposes + gather + VP pad ----
__device__ void txw_tile(const float* __restrict__ src, u16* __restrict__ dst,
                         int K, int N, int Kpad, int k0, int n0, int t,
                         float (*tileS)[65]) {
  __syncthreads();  // protect LDS across task iterations
  {
    const int kr = t >> 2, nc = (t & 3) * 16;
    const int k = k0 + kr;
#pragma unroll
    for (int j = 0; j < 16; j += 4) {
      float4 v = (k < K) ? ld4(src + (size_t)k * N + n0 + nc + j)
                         : make_float4(0.f, 0.f, 0.f, 0.f);
      tileS[kr][nc + j + 0] = v.x; tileS[kr][nc + j + 1] = v.y;
      tileS[kr][nc + j + 2] = v.z; tileS[kr][nc + j + 3] = v.w;
    }
  }
  __syncthreads();
  {
    const int nr = t >> 2, kc = (t & 3) * 16;
    us8 o0, o1;
#pragma unroll
    for (int j = 0; j < 8; ++j) {
      o0[j] = f2bf(tileS[kc + j][nr]);
      o1[j] = f2bf(tileS[kc + 8 + j][nr]);
    }
    u16* d = dst + (size_t)(n0 + nr) * Kpad + k0 + kc;
    *(us8*)d = o0;
    *(us8*)(d + 8) = o1;
  }
}

__global__ __launch_bounds__(256)
void k_prep(const float* __restrict__ W1f, const float* __restrict__ W1r,
            const float* __restrict__ W2, const float* __restrict__ Wg,
            const float* __restrict__ Wf1, const float* __restrict__ Wf2,
            u16* __restrict__ Wt1f, u16* __restrict__ Wt1r,
            u16* __restrict__ Wt2, u16* __restrict__ Wtg,
            u16* __restrict__ Wf1t, u16* __restrict__ Wf2t,
            const float* __restrict__ embed, const int* __restrict__ ids1,
            const int* __restrict__ ids2, u16* __restrict__ X1,
            u16* __restrict__ X2, u16* __restrict__ VPh, u16* __restrict__ VPl) {
  __shared__ float tileS[64][65];
  const int t = threadIdx.x;
  const int blk = blockIdx.x, nblk = gridDim.x;
  for (int it = blk; it < 20; it += nblk)
    txw_tile(W1f, Wt1f, 300, 256, 320, (it % 5) * 64, (it / 5) * 64, t, tileS);
  for (int it = blk; it < 144; it += nblk) {
    const int l = it / 16, r = it % 16;
    txw_tile(W1r + (size_t)l * 65536, Wt1r + (size_t)l * 65536, 256, 256, 256,
             (r % 4) * 64, (r / 4) * 64, t, tileS);
  }
  for (int it = blk; it < 320; it += nblk) {
    const int l = it / 32, r = it % 32;
    txw_tile(W2 + (size_t)l * 131072, Wt2 + (size_t)l * 131072, 512, 256, 512,
             (r % 8) * 64, (r / 8) * 64, t, tileS);
  }
  for (int it = blk; it < 160; it += nblk) {
    const int l = it / 16, r = it % 16;
    txw_tile(Wg + (size_t)l * 65536, Wtg + (size_t)l * 65536, 256, 256, 256,
             (r % 4) * 64, (r / 4) * 64, t, tileS);
  }
  for (int it = blk; it < 256; it += nblk)
    txw_tile(Wf1, Wf1t, 1024, 1024, 1024, (it % 16) * 64, (it / 16) * 64, t, tileS);
  for (int it = blk; it < 256; it += nblk)
    txw_tile(Wf2, Wf2t, 1024, 1024, 1024, (it % 16) * 64, (it / 16) * 64, t, tileS);
  for (int g = blk; g < 4096; g += nblk) {
    const int side = g & 1;
    const int* ids = side ? ids2 : ids1;
    u16* E = side ? X2 : X1;
    const int row = (g >> 1) * 4 + (t >> 6);
    const int lane = t & 63;
    const float* src = embed + (size_t)ids[row] * EE;
    u16* dst = E + (size_t)row * 320;
#pragma unroll
    for (int j = 0; j < 5; ++j) {
      const int c = lane + 64 * j;
      dst[c] = f2bf(c < EE ? src[c] : 0.f);
    }
  }
  // zero the MLP pad rows 64..127 of VPh/VPl
  for (int it = blk; it < 128; it += nblk) {
    const int arr = it & 1, row = 64 + (it >> 1);
    u16* dst = (arr ? VPl : VPh) + (size_t)row * 1024;
#pragma unroll
    for (int j = 0; j < 4; ++j) dst[t * 4 + j] = 0;
  }
}

// ---------------- LBR-1 n64 (LDS dbuf, +H^T epilogue, +sq-norm partials) -
__global__ __launch_bounds__(256, 2)
void mfma_lbr(const u16* __restrict__ A0, const u16* __restrict__ A1, int lda,
              int K, const u16* __restrict__ Wt, const float* __restrict__ bias,
              const float* __restrict__ gam, const float* __restrict__ bet,
              u16* __restrict__ O0, u16* __restrict__ O1,
              u16* __restrict__ HTa, u16* __restrict__ HTb,
              float* __restrict__ SQPa, float* __restrict__ SQPb) {
  const int side = blockIdx.z;
  const u16* A = side ? A1 : A0;
  u16* O = side ? O1 : O0;
  u16* HT = side ? HTb : HTa;
  float* SQP = side ? SQPb : SQPa;
  __shared__ u16 As[2][4096], Bs[2][2048];
  const int t = threadIdx.x;
  const int m0 = blockIdx.x * 128, n0 = blockIdx.y * 64;
  const int lane = t & 63, w = t >> 6, wm = w >> 1, wn = w & 1;
  const int fr = lane & 15, fq = lane >> 4;
  f4 acc[4][2] = {};
  const int nt = K / 32;
  stage_tile(A, lda, m0, 0, As[0], t);
  stage_tile64(Wt, K, n0, 0, Bs[0], t);
  __syncthreads();
  for (int ks = 0; ks < nt; ++ks) {
    const int cur = ks & 1;
    if (ks + 1 < nt) {
      stage_tile(A, lda, m0, (ks + 1) * 32, As[cur ^ 1], t);
      stage_tile64(Wt, K, n0, (ks + 1) * 32, Bs[cur ^ 1], t);
    }
    mfma_step_n64(As[cur], Bs[cur], wm, wn, fr, fq, acc);
    __syncthreads();
  }
  const int b = m0 >> 7;
  float rsq[4][4] = {};
#pragma unroll
  for (int nj = 0; nj < 2; ++nj) {
    const int n = n0 + wn * 32 + nj * 16 + fr;
    const float sc = gam[n] * BN_SC, bi = bias[n], be = bet[n];
#pragma unroll
    for (int mi = 0; mi < 4; ++mi) {
      const int m = m0 + wm * 64 + mi * 16 + fq * 4;
      us4 pk;
#pragma unroll
      for (int r = 0; r < 4; ++r) {
        const float x = sc * (acc[mi][nj][r] + bi) + be;
        const u16 hb = f2bf(fmaxf(x, 0.f));
        O[(size_t)(m + r) * DD + n] = hb;
        pk[r] = hb;
        const float h = bf2f(hb);  // norms must match stored bf16 H
        rsq[mi][r] += h * h;
      }
      *(us4*)&HT[((size_t)b * DD + n) * LL + (m & 127)] = pk;
    }
  }
#pragma unroll
  for (int mi = 0; mi < 4; ++mi)
#pragma unroll
    for (int r = 0; r < 4; ++r) {
      float v = rsq[mi][r];
      v += __shfl_xor(v, 1, 64); v += __shfl_xor(v, 2, 64);
      v += __shfl_xor(v, 4, 64); v += __shfl_xor(v, 8, 64);
      rsq[mi][r] = v;
    }
  if (fr == 0) {
    const int p = blockIdx.y * 2 + wn;  // 8 partials per row
#pragma unroll
    for (int mi = 0; mi < 4; ++mi)
#pragma unroll
      for (int r = 0; r < 4; ++r)
        SQP[(size_t)p * MROWS + m0 + wm * 64 + mi * 16 + fq * 4 + r] = rsq[mi][r];
  }
}

// ------- fused att+attn per (batch, N-half, side): E in LDS, PV out ------
__global__ __launch_bounds__(256, 2)
void attf(const u16* __restrict__ H1, const u16* __restrict__ H2,
          const float* __restrict__ SQP1, const float* __restrict__ SQP2,
          const u16* __restrict__ HT1, const u16* __restrict__ HT2,
          u16* __restrict__ BETA, u16* __restrict__ ALPHA) {
  const int b = blockIdx.x, nh = blockIdx.y, side = blockIdx.z;
  __shared__ u16 Elds[128 * 128];  // 32KB swizzled (Ê or Ê^T per side)
  __shared__ float sqs[2][128], rowp[2][128], colp[2][128];
  const int t = threadIdx.x, lane = t & 63, w = t >> 6;
  const int wm = w >> 1, wn = w & 1;
  const int fr = lane & 15, fq = lane >> 4;
  const int r0 = b * LL;
  if (t < 128) {
    float s = 0.f;
#pragma unroll
    for (int p = 0; p < 8; ++p) s += SQP1[(size_t)p * MROWS + r0 + t];
    sqs[0][t] = s;
  } else {
    const int u = t - 128;
    float s = 0.f;
#pragma unroll
    for (int p = 0; p < 8; ++p) s += SQP2[(size_t)p * MROWS + r0 + u];
    sqs[1][u] = s;
  }
  // QK^T: full 128x128 E, no-LDS frag loads
  f4 acc[4][4] = {};
#pragma unroll
  for (int ks = 0; ks < 8; ++ks) {
    bfrag a[4], bv[4];
#pragma unroll
    for (int mi = 0; mi < 4; ++mi)
      a[mi] = gfrag(H1, DD, r0 + wm * 64 + mi * 16 + fr, ks * 32 + fq * 8);
#pragma unroll
    for (int nj = 0; nj < 4; ++nj)
      bv[nj] = gfrag(H2, DD, r0 + wn * 64 + nj * 16 + fr, ks * 32 + fq * 8);
#pragma unroll
    for (int mi = 0; mi < 4; ++mi)
#pragma unroll
      for (int nj = 0; nj < 4; ++nj) acc[mi][nj] = MFMA_B16(a[mi], bv[nj], acc[mi][nj]);
  }
  __syncthreads();  // sqs visible
  float rp[4][4] = {}, cp[4] = {};
#pragma unroll
  for (int nj = 0; nj < 4; ++nj) {
    const int n = wn * 64 + nj * 16 + fr;
    const float s2 = sqs[1][n];
#pragma unroll
    for (int mi = 0; mi < 4; ++mi) {
      const int m = wm * 64 + mi * 16 + fq * 4;
#pragma unroll
      for (int r = 0; r < 4; ++r) {
        const float d = sqs[0][m + r] + s2 - 2.f * acc[mi][nj][r];
        const float e = __expf(1.f / (1.f + d));
        acc[mi][nj][r] = e;
        rp[mi][r] += e;
        cp[nj] += e;
      }
    }
  }
#pragma unroll
  for (int mi = 0; mi < 4; ++mi)
#pragma unroll
    for (int r = 0; r < 4; ++r) {
      float v = rp[mi][r];
      v += __shfl_xor(v, 1, 64); v += __shfl_xor(v, 2, 64);
      v += __shfl_xor(v, 4, 64); v += __shfl_xor(v, 8, 64);
      rp[mi][r] = v;
    }
#pragma unroll
  for (int nj = 0; nj < 4; ++nj) {
    float v = cp[nj];
    v += __shfl_xor(v, 16, 64); v += __shfl_xor(v, 32, 64);
    cp[nj] = v;
  }
  if (fr == 0)
#pragma unroll
    for (int mi = 0; mi < 4; ++mi)
#pragma unroll
      for (int r = 0; r < 4; ++r)
        rowp[wn][wm * 64 + mi * 16 + fq * 4 + r] = rp[mi][r];
  if (fq == 0)
#pragma unroll
    for (int nj = 0; nj < 4; ++nj)
      colp[wm][wn * 64 + nj * 16 + fr] = cp[nj];
  __syncthreads();
  if (side == 0) {  // row-normalized Ê
#pragma unroll
    for (int nj = 0; nj < 4; ++nj) {
      const int n = wn * 64 + nj * 16 + fr;
#pragma unroll
      for (int mi = 0; mi < 4; ++mi) {
        const int m = wm * 64 + mi * 16 + fq * 4;
#pragma unroll
        for (int r = 0; r < 4; ++r) {
          const float riv = 1.f / (rowp[0][m + r] + rowp[1][m + r]);
          *(u16*)((char*)Elds + eswz(m + r, n * 2)) = f2bf(acc[mi][nj][r] * riv);
        }
      }
    }
  } else {  // col-normalized Ê^T
#pragma unroll
    for (int nj = 0; nj < 4; ++nj) {
      const int n = wn * 64 + nj * 16 + fr;
      const float civ = 1.f / (colp[0][n] + colp[1][n]);
#pragma unroll
      for (int mi = 0; mi < 4; ++mi) {
        const int m = wm * 64 + mi * 16 + fq * 4;
        us4 pk;
#pragma unroll
        for (int r = 0; r < 4; ++r) pk[r] = f2bf(acc[mi][nj][r] * civ);
        *(us4*)((char*)Elds + eswz(n, m * 2)) = pk;
      }
    }
  }
  __syncthreads();
  // PV: O = Ê @ H (B-frags from HT rows = H columns), this block's 128-col half
  const u16* HT = side ? HT1 : HT2;
  f4 pv[4][4] = {};
#pragma unroll
  for (int ks = 0; ks < 4; ++ks) {
    bfrag a[4], bv[4];
#pragma unroll
    for (int mi = 0; mi < 4; ++mi)
      a[mi] = ldsE(Elds, wm * 64 + mi * 16 + fr, ks * 64 + fq * 16);
#pragma unroll
    for (int nj = 0; nj < 4; ++nj)
      bv[nj] = gfrag(HT, LL, b * DD + nh * 128 + wn * 64 + nj * 16 + fr, ks * 32 + fq * 8);
#pragma unroll
    for (int mi = 0; mi < 4; ++mi)
#pragma unroll
      for (int nj = 0; nj < 4; ++nj) pv[mi][nj] = MFMA_B16(a[mi], bv[nj], pv[mi][nj]);
  }
  u16* O = side ? ALPHA : BETA;
#pragma unroll
  for (int nj = 0; nj < 4; ++nj) {
    const int n = nh * 128 + wn * 64 + nj * 16 + fr;
#pragma unroll
    for (int mi = 0; mi < 4; ++mi) {
      const int m = wm * 64 + mi * 16 + fq * 4;
#pragma unroll
      for (int r = 0; r < 4; ++r)
        O[(size_t)(r0 + m + r) * DD + n] = f2bf(pv[mi][nj][r]);
    }
  }
}

// -------- vg n64: fused W2 || Wg + gate update (+pool on last layer) -----
__global__ __launch_bounds__(256, 2)
void mfma_vg(const u16* __restrict__ Hbf1, const u16* __restrict__ Hbf2,
             const u16* __restrict__ BETA, const u16* __restrict__ ALPHA,
             const u16* __restrict__ Wt2, const u16* __restrict__ Wtg,
             const float* __restrict__ b2, const float* __restrict__ g2,
             const float* __restrict__ be2, const float* __restrict__ bgv,
             u16* __restrict__ X0, u16* __restrict__ X1p, int dopool,
             u16* __restrict__ VPh, u16* __restrict__ VPl) {
  const int side = blockIdx.z;
  const u16* H = side ? Hbf2 : Hbf1;
  const u16* CC = side ? ALPHA : BETA;
  u16* X = side ? X1p : X0;
  const int m0 = blockIdx.x * 128, n0 = blockIdx.y * 64;
  __shared__ u16 As[2][4096], B2s[2][2048], Bgs[2][2048];
  __shared__ float pmx[2][64], psm[2][64];
  const int t = threadIdx.x;
  const int lane = t & 63, w = t >> 6, wm = w >> 1, wn = w & 1;
  const int fr = lane & 15, fq = lane >> 4;
  f4 accv[4][2] = {}, accg[4][2] = {};
  stage_tile(H, DD, m0, 0, As[0], t);
  stage_tile64(Wt2, 2 * DD, n0, 0, B2s[0], t);
  stage_tile64(Wtg, DD, n0, 0, Bgs[0], t);
  __syncthreads();
  for (int ks = 0; ks < 16; ++ks) {
    const int cur = ks & 1;
    if (ks + 1 < 16) {
      const u16* Asrc = (ks + 1 < 8) ? H : CC;
      stage_tile(Asrc, DD, m0, ((ks + 1) & 7) * 32, As[cur ^ 1], t);
      stage_tile64(Wt2, 2 * DD, n0, (ks + 1) * 32, B2s[cur ^ 1], t);
      if (ks + 1 < 8) stage_tile64(Wtg, DD, n0, (ks + 1) * 32, Bgs[cur ^ 1], t);
    }
    if (ks < 8)
      mfma_step2_n64(As[cur], B2s[cur], Bgs[cur], wm, wn, fr, fq, accv, accg);
    else
      mfma_step_n64(As[cur], B2s[cur], wm, wn, fr, fq, accv);
    __syncthreads();
  }
  float pmax[2] = {-1e30f, -1e30f}, psum[2] = {0.f, 0.f};
#pragma unroll
  for (int nj = 0; nj < 2; ++nj) {
    const int n = n0 + wn * 32 + nj * 16 + fr;
    const float sc = g2[n] * BN_SC, bi = b2[n], be = be2[n], bgn = bgv[n];
#pragma unroll
    for (int mi = 0; mi < 4; ++mi) {
      const int m = m0 + wm * 64 + mi * 16 + fq * 4;
#pragma unroll
      for (int r = 0; r < 4; ++r) {
        const float v = fmaxf(sc * (accv[mi][nj][r] + bi) + be, 0.f);
        const float g = 1.f / (1.f + __expf(-(accg[mi][nj][r] + bgn)));
        const float h = bf2f(H[(size_t)(m + r) * DD + n]);
        const u16 xb = f2bf(v * g + h * (1.f - g));
        X[(size_t)(m + r) * DD + n] = xb;
        if (dopool) {
          const float xv = bf2f(xb);
          pmax[nj] = fmaxf(pmax[nj], xv);
          psum[nj] += xv;
        }
      }
    }
  }
  if (dopool) {
    // reduce over fq (lane bits 4,5), then across wm via LDS
#pragma unroll
    for (int nj = 0; nj < 2; ++nj) {
      float mx = pmax[nj], sm = psum[nj];
      mx = fmaxf(mx, __shfl_xor(mx, 16, 64)); sm += __shfl_xor(sm, 16, 64);
      mx = fmaxf(mx, __shfl_xor(mx, 32, 64)); sm += __shfl_xor(sm, 32, 64);
      if (fq == 0) {
        pmx[wm][wn * 32 + nj * 16 + fr] = mx;
        psm[wm][wn * 32 + nj * 16 + fr] = sm;
      }
    }
    __syncthreads();
    if (t < 64) {
      const float mx = fmaxf(pmx[0][t], pmx[1][t]);
      const float sm = psm[0][t] + psm[1][t];
      const int b = m0 >> 7;
      const int col = n0 + t;
      const u16 mh = f2bf(mx);
      VPh[(size_t)b * 1024 + side * 256 + col] = mh;
      VPl[(size_t)b * 1024 + side * 256 + col] = f2bf(mx - bf2f(mh));
      const u16 sh = f2bf(sm);
      VPh[(size_t)b * 1024 + (2 + side) * 256 + col] = sh;
      VPl[(size_t)b * 1024 + (2 + side) * 256 + col] = f2bf(sm - bf2f(sh));
    }
  }
}

// ---------------- MLP split-K no-LDS: PART[slice] = (Ah+Al) @ Wt-slice ---
__global__ __launch_bounds__(256, 2)
void mlp_sk(const u16* __restrict__ Ah, const u16* __restrict__ Al,
            const u16* __restrict__ Wt, float* __restrict__ PART) {
  const int n0 = blockIdx.x * 128;   // 8 N-blocks
  const int k0 = blockIdx.y * 128;   // 8 K-slices
  const int t = threadIdx.x, lane = t & 63, w = t >> 6;
  const int wm = w >> 1, wn = w & 1;
  const int fr = lane & 15, fq = lane >> 4;
  f4 acc[4][4] = {};
#pragma unroll
  for (int ks = 0; ks < 4; ++ks) {
    bfrag ah[4], al[4], bv[4];
#pragma unroll
    for (int mi = 0; mi < 4; ++mi) {
      ah[mi] = gfrag(Ah, 1024, wm * 64 + mi * 16 + fr, k0 + ks * 32 + fq * 8);
      al[mi] = gfrag(Al, 1024, wm * 64 + mi * 16 + fr, k0 + ks * 32 + fq * 8);
    }
#pragma unroll
    for (int nj = 0; nj < 4; ++nj)
      bv[nj] = gfrag(Wt, 1024, n0 + wn * 64 + nj * 16 + fr, k0 + ks * 32 + fq * 8);
#pragma unroll
    for (int mi = 0; mi < 4; ++mi)
#pragma unroll
      for (int nj = 0; nj < 4; ++nj) {
        acc[mi][nj] = MFMA_B16(ah[mi], bv[nj], acc[mi][nj]);
        acc[mi][nj] = MFMA_B16(al[mi], bv[nj], acc[mi][nj]);
      }
  }
#pragma unroll
  for (int nj = 0; nj < 4; ++nj) {
    const int n = n0 + wn * 64 + nj * 16 + fr;
#pragma unroll
    for (int mi = 0; mi < 4; ++mi) {
      const int m = wm * 64 + mi * 16 + fq * 4;
#pragma unroll
      for (int r = 0; r < 4; ++r)
        PART[((size_t)blockIdx.y * 128 + m + r) * 1024 + n] = acc[mi][nj][r];
    }
  }
}

// combine 8 partials + bias + relu -> hi/lo bf16 (or fp32)
__global__ __launch_bounds__(512)
void mlp_comb(const float* __restrict__ P, const float* __restrict__ bias,
              u16* __restrict__ Oh, u16* __restrict__ Ol,
              float* __restrict__ Of) {
#pragma unroll
  for (int e = 0; e < 8; ++e) {
    const int idx = blockIdx.x * 4096 + e * 512 + threadIdx.x;
    const int col = idx & 1023;
    float s = bias[col];
#pragma unroll
    for (int p = 0; p < 8; ++p) s += P[(size_t)p * 131072 + idx];
    s = fmaxf(s, 0.f);
    if (Oh) {
      const u16 h = f2bf(s);
      Oh[idx] = h;
      Ol[idx] = f2bf(s - bf2f(h));
    } else {
      Of[idx] = s;
    }
  }
}

__global__ __launch_bounds__(256)
void out_kernel(const float* __restrict__ T2, const float* __restrict__ Wout,
                const float* __restrict__ bout, float* __restrict__ out) {
  const int b = blockIdx.x;
  const int t = threadIdx.x;  // 256
  float a0 = 0.f, a1 = 0.f, a2 = 0.f;
  for (int k = t; k < 1024; k += 256) {
    const float x = T2[(size_t)b * 1024 + k];
    a0 = fmaf(x, Wout[k * 3 + 0], a0);
    a1 = fmaf(x, Wout[k * 3 + 1], a1);
    a2 = fmaf(x, Wout[k * 3 + 2], a2);
  }
  __shared__ float red[3][256];
  red[0][t] = a0; red[1][t] = a1; red[2][t] = a2;
  __syncthreads();
  for (int off = 128; off > 0; off >>= 1) {
    if (t < off) {
      red[0][t] += red[0][t + off];
      red[1][t] += red[1][t + off];
      red[2][t] += red[2][t + off];
    }
    __syncthreads();
  }
  if (t < 3) out[b * 3 + t] = red[t][0] + bout[t];
}

extern "C" void kernel_launch(void* const* d_in, const int* in_sizes, int n_in,
                              void* d_out, int out_size, void* d_ws, size_t ws_size,
                              hipStream_t stream) {
  (void)in_sizes; (void)n_in; (void)out_size; (void)ws_size;
  const float* embed = (const float*)d_in[0];
  const float* W1f   = (const float*)d_in[1];
  const float* W1r   = (const float*)d_in[2];
  const float* b1    = (const float*)d_in[3];
  const float* bn1g  = (const float*)d_in[4];
  const float* bn1b  = (const float*)d_in[5];
  const float* W2    = (const float*)d_in[6];
  const float* b2    = (const float*)d_in[7];
  const float* bn2g  = (const float*)d_in[8];
  const float* bn2b  = (const float*)d_in[9];
  const float* Wg    = (const float*)d_in[10];
  const float* bg    = (const float*)d_in[11];
  const float* Wf1   = (const float*)d_in[12];
  const float* bf1   = (const float*)d_in[13];
  const float* Wf2   = (const float*)d_in[14];
  const float* bf2   = (const float*)d_in[15];
  const float* Wout  = (const float*)d_in[16];
  const float* bout  = (const float*)d_in[17];
  const int* ids1    = (const int*)d_in[18];
  const int* ids2    = (const int*)d_in[19];

  char* wsp = (char*)d_ws;
  auto alloc = [&](size_t bytes) {
    char* p = wsp;
    wsp += (bytes + 255) & ~(size_t)255;
    return p;
  };
  u16* Hbf1  = (u16*)alloc((size_t)MROWS * DD * 2);
  u16* Hbf2  = (u16*)alloc((size_t)MROWS * DD * 2);
  u16* HT1   = (u16*)alloc((size_t)MROWS * DD * 2);
  u16* HT2   = (u16*)alloc((size_t)MROWS * DD * 2);
  u16* Xbf1  = (u16*)alloc((size_t)MROWS * 320 * 2);
  u16* Xbf2  = (u16*)alloc((size_t)MROWS * 320 * 2);
  u16* BETAb = (u16*)alloc((size_t)MROWS * DD * 2);
  u16* ALPHAb= (u16*)alloc((size_t)MROWS * DD * 2);
  float* SQP1= (float*)alloc((size_t)8 * MROWS * 4);
  float* SQP2= (float*)alloc((size_t)8 * MROWS * 4);
  u16* Wt1f  = (u16*)alloc((size_t)DD * 320 * 2);
  u16* Wt1r  = (u16*)alloc((size_t)9 * DD * DD * 2);
  u16* Wt2   = (u16*)alloc((size_t)10 * DD * 2 * DD * 2);
  u16* Wtg   = (u16*)alloc((size_t)10 * DD * DD * 2);
  u16* Wf1t  = (u16*)alloc((size_t)1024 * 1024 * 2);
  u16* Wf2t  = (u16*)alloc((size_t)1024 * 1024 * 2);
  u16* VPh   = (u16*)alloc((size_t)128 * 1024 * 2);
  u16* VPl   = (u16*)alloc((size_t)128 * 1024 * 2);
  u16* T1h   = (u16*)alloc((size_t)128 * 1024 * 2);
  u16* T1l   = (u16*)alloc((size_t)128 * 1024 * 2);
  float* T2f = (float*)alloc((size_t)128 * 1024 * 4);
  float* PART1 = (float*)alloc((size_t)8 * 128 * 1024 * 4);
  float* PART2 = (float*)alloc((size_t)8 * 128 * 1024 * 4);

  k_prep<<<512, 256, 0, stream>>>(W1f, W1r, W2, Wg, Wf1, Wf2,
                                  Wt1f, Wt1r, Wt2, Wtg, Wf1t, Wf2t,
                                  embed, ids1, ids2, Xbf1, Xbf2, VPh, VPl);

  for (int i = 0; i < NLAYERS; ++i) {
    const u16* Wt1 = (i == 0) ? Wt1f : (Wt1r + (size_t)(i - 1) * DD * DD);
    const int K1 = (i == 0) ? 320 : DD;
    mfma_lbr<<<dim3(MROWS / 128, 4, 2), 256, 0, stream>>>(
        Xbf1, Xbf2, K1, K1, Wt1, b1 + i * DD, bn1g + i * DD, bn1b + i * DD,
        Hbf1, Hbf2, HT1, HT2, SQP1, SQP2);
    attf<<<dim3(NB, 2, 2), 256, 0, stream>>>(Hbf1, Hbf2, SQP1, SQP2, HT1, HT2,
                                             BETAb, ALPHAb);
    mfma_vg<<<dim3(MROWS / 128, 4, 2), 256, 0, stream>>>(
        Hbf1, Hbf2, BETAb, ALPHAb, Wt2 + (size_t)i * DD * 2 * DD,
        Wtg + (size_t)i * DD * DD, b2 + i * DD, bn2g + i * DD, bn2b + i * DD,
        bg + i * DD, Xbf1, Xbf2, (i == NLAYERS - 1) ? 1 : 0, VPh, VPl);
  }
  mlp_sk<<<dim3(8, 8), 256, 0, stream>>>(VPh, VPl, Wf1t, PART1);
  mlp_comb<<<32, 512, 0, stream>>>(PART1, bf1, T1h, T1l, nullptr);
  mlp_sk<<<dim3(8, 8), 256, 0, stream>>>(T1h, T1l, Wf2t, PART2);
  mlp_comb<<<32, 512, 0, stream>>>(PART2, bf2, nullptr, nullptr, T2f);
  out_kernel<<<NB, 256, 0, stream>>>(T2f, Wout, bout, (float*)d_out);
}